// Round 8
// baseline (5030.910 us; speedup 1.0000x reference)
//
#include <hip/hip_runtime.h>
#include <hip/hip_bf16.h>

#define DEV __device__ __forceinline__

namespace {

constexpr int ROWS = 64 * 4096;        // B*T
constexpr int NE   = ROWS * 64;        // B*T*F
constexpr int CHUNK = 512;
constexpr int NCHUNK = 4096 / CHUNK;   // 8

constexpr size_t GXCH = (size_t)64 * CHUNK * 384;   // elems per gx chunk buf
constexpr size_t RCH  = (size_t)64 * CHUNK * 128;   // elems per z/r1/r2 chunk buf

// workspace layout (bytes), total ~185.1 MB
constexpr size_t OFF_XC  = 0;            // bf16 NE          33,554,432
constexpr size_t OFF_MC  = 33554432;     // u8 NE            16,777,216
constexpr size_t OFF_WC  = 50331648;     // fp32 weights
constexpr size_t OFF_ACC = 50862080;     // 4 KB acc/flags
constexpr size_t OFF_H2  = 50866176;     // f16 NE           33,554,432
constexpr size_t OFF_GX  = 84420608;     // f16 2*GXCH       50,331,648
constexpr size_t OFF_ZR  = 134752256;    // f16 2*RCH        16,777,216
constexpr size_t OFF_R1  = 151529472;    // f16 2*RCH
constexpr size_t OFF_R2  = 168306688;    // f16 2*RCH
constexpr size_t OFF_HST = 185083904;    // fp32 64*128

DEV float rlane(float v, int l) {
    return __int_as_float(__builtin_amdgcn_readlane(__float_as_int(v), l));
}
DEV unsigned int rlu(unsigned int v, int l) {
    return (unsigned int)__builtin_amdgcn_readlane((int)v, l);
}
DEV float bf2f(unsigned short u) { return __uint_as_float(((unsigned int)u) << 16); }
DEV unsigned short f2bf(float f) {
    unsigned int u = __float_as_uint(f);
    unsigned int r = (u + 0x7FFFu + ((u >> 16) & 1u)) >> 16;
    return (unsigned short)r;
}
DEV float gelu_f(float v) { return 0.5f * v * (1.0f + erff(v * 0.70710678118654752f)); }
DEV float sigm_f(float x) { return 1.0f / (1.0f + __expf(-x)); }
DEV float tanh_f(float x) { float t = __expf(2.0f * x); return 1.0f - 2.0f / (t + 1.0f); }

typedef _Float16 half2v __attribute__((ext_vector_type(2)));
typedef __attribute__((ext_vector_type(8))) short bf16x8;
typedef __attribute__((ext_vector_type(4))) float f32x4;

DEV float dot2(half2v a, half2v b, float c) {
#if __has_builtin(__builtin_amdgcn_fdot2)
    return __builtin_amdgcn_fdot2(a, b, c, false);
#else
    return c + (float)a.x * (float)b.x + (float)a.y * (float)b.y;
#endif
}
DEV unsigned short f2h_bits(float f) {
    return __builtin_bit_cast(unsigned short, (_Float16)f);
}
DEV float h2f_bits(unsigned short u) {
    return (float)__builtin_bit_cast(_Float16, u);
}
DEV half2v u2h2(unsigned int p) { return __builtin_bit_cast(half2v, p); }
// LDS-only barrier: skips the vmcnt(0) drain __syncthreads would emit.
DEV void bar_lds() {
    asm volatile("s_waitcnt lgkmcnt(0)\n\ts_barrier" ::: "memory");
}

} // namespace

// ---------------- dtype probe (memory-safe) ----------------
__global__ __launch_bounds__(256) void k_probe(const unsigned short* __restrict__ xh,
    const unsigned char* __restrict__ mb, int* __restrict__ cnt)
{
    const int g = blockIdx.x * 256 + threadIdx.x;
    int hit = 0;
    for (int i = g; i < (1 << 20); i += (1 << 16)) {
        int tb = (xh[i] >> 8) & 0x7F;
        hit += (tb >= 0x3C && tb <= 0x40) ? 1 : 0;
    }
    int a = 0, b = 0, c = 0, d = 0;
    for (int i = g; i < (1 << 24); i += (1 << 16)) {
        unsigned char v = mb[i];
        int r = i & 3;
        a += (v == 1    && r == 0) ? 1 : 0;
        b += (v == 1    && r != 0) ? 1 : 0;
        c += (v == 0x80 && r == 0) ? 1 : 0;
        d += (v == 0x80 && r == 2) ? 1 : 0;
    }
    __shared__ int sm[256];
    int vals[5] = {hit, a, b, c, d};
#pragma unroll
    for (int k = 0; k < 5; ++k) {
        sm[threadIdx.x] = vals[k];
        __syncthreads();
        for (int s = 128; s > 0; s >>= 1) {
            if (threadIdx.x < s) sm[threadIdx.x] += sm[threadIdx.x + s];
            __syncthreads();
        }
        if (threadIdx.x == 0) atomicAdd(cnt + k, sm[0]);
        __syncthreads();
    }
}

__global__ void k_classify(const int* __restrict__ cnt, int* __restrict__ flags)
{
    flags[0] = (cnt[0] > 786432) ? 0 : 1;
    int fm;
    if (cnt[2] > 0) fm = 0;
    else if (cnt[1] > 0) fm = 1;
    else if (cnt[3] > 0) fm = 2;
    else if (cnt[4] > 0) fm = 3;
    else fm = 0;
    flags[1] = fm;
}

// ---------------- canonicalize x (bf16) + mask (u8) ----------------
__global__ __launch_bounds__(256) void k_canon_x(const void* __restrict__ x,
    const void* __restrict__ mask, unsigned short* __restrict__ xc,
    unsigned char* __restrict__ mc, const int* __restrict__ flags)
{
    const int fF = flags[0], fM = flags[1];
    for (int i = blockIdx.x * 256 + threadIdx.x; i < NE; i += gridDim.x * 256) {
        unsigned short h;
        if (fF == 0) h = ((const unsigned short*)x)[i];
        else         h = f2bf(((const float*)x)[i]);
        xc[i] = h;
        unsigned char m;
        if (fM == 0)      m = (((const unsigned char*)mask)[i]  != 0) ? 1 : 0;
        else if (fM == 1) m = (((const int*)mask)[i]            != 0) ? 1 : 0;
        else if (fM == 2) m = (((const unsigned short*)mask)[i] != 0) ? 1 : 0;
        else              m = (((const unsigned int*)mask)[i]   != 0) ? 1 : 0;
        mc[i] = m;
    }
}

// ---------------- canonicalize weights to fp32 ----------------
__global__ __launch_bounds__(256) void k_canon_w(
    const void* p0, const void* p1, const void* p2, const void* p3,
    const void* p4, const void* p5, const void* p6, const void* p7,
    const void* p8, const void* p9, const void* p10, const void* p11,
    const void* p12, const void* p13, float* __restrict__ wc,
    const int* __restrict__ flags)
{
    const int fF = flags[0];
    const void* p; int off, n;
    switch (blockIdx.x) {
        case 0:  p = p0;  off = 0;      n = 4096;  break;  // stem_w
        case 1:  p = p1;  off = 4096;   n = 64;    break;  // stem_b
        case 2:  p = p2;  off = 4160;   n = 12288; break;  // conv_w
        case 3:  p = p3;  off = 16448;  n = 64;    break;  // conv_b
        case 4:  p = p4;  off = 16512;  n = 24576; break;  // w_ih
        case 5:  p = p5;  off = 41088;  n = 49152; break;  // w_hh
        case 6:  p = p6;  off = 90240;  n = 384;   break;  // b_ih
        case 7:  p = p7;  off = 90624;  n = 384;   break;  // b_hh
        case 8:  p = p8;  off = 91008;  n = 16384; break;  // h1_w
        case 9:  p = p9;  off = 107392; n = 128;   break;  // h1_b
        case 10: p = p10; off = 107520; n = 16384; break;  // h2_w
        case 11: p = p11; off = 123904; n = 128;   break;  // h2_b
        case 12: p = p12; off = 124032; n = 8192;  break;  // h3_w
        default: p = p13; off = 132224; n = 64;    break;  // h3_b
    }
    for (int i = threadIdx.x; i < n; i += 256) {
        float v = (fF == 0) ? bf2f(((const unsigned short*)p)[i]) : ((const float*)p)[i];
        wc[off + i] = v;
    }
}

// ---------------- std over features + mask count ----------------
__global__ __launch_bounds__(256) void k_std(const unsigned short* __restrict__ xc,
    const unsigned char* __restrict__ mc, double* __restrict__ acc)
{
    const int tid = threadIdx.x, f = tid & 63, slot = tid >> 6;
    float s = 0.f, sq = 0.f; int cnt = 0;
    for (int row = blockIdx.x * 4 + slot; row < ROWS; row += gridDim.x * 4) {
        const size_t base = (size_t)row * 64 + f;
        float v = bf2f(xc[base]);
        s += v; sq += v * v;
        cnt += mc[base];
    }
    __shared__ float ls[256], lq[256];
    __shared__ int lc[256];
    ls[tid] = s; lq[tid] = sq; lc[tid] = cnt;
    __syncthreads();
    if (tid < 64) {
        float S = ls[tid] + ls[tid + 64] + ls[tid + 128] + ls[tid + 192];
        float Q = lq[tid] + lq[tid + 64] + lq[tid + 128] + lq[tid + 192];
        atomicAdd(acc + tid, (double)S);
        atomicAdd(acc + 64 + tid, (double)Q);
    }
    if (tid == 0) {
        int tot = 0;
        for (int i = 0; i < 256; ++i) tot += lc[i];
        atomicAdd(acc + 128, (double)tot);
    }
}

__global__ void k_scale(const double* __restrict__ acc, float* __restrict__ inv2)
{
    int f = threadIdx.x;
    const double N = (double)ROWS;
    double sum = acc[f], sq = acc[64 + f];
    double var = (sq - sum * sum / N) / (N - 1.0);
    double sd = sqrt(var) + 1e-8;
    inv2[f] = (float)(1.0 / (sd * sd));
}

// ---------------- fused stem + conv via MFMA ----------------
__global__ __launch_bounds__(512) void k_stemconv(const unsigned short* __restrict__ xc,
    const unsigned char* __restrict__ mc, const float* __restrict__ sw,
    const float* __restrict__ sb, const float* __restrict__ cw,
    const float* __restrict__ cb, unsigned short* __restrict__ h2)
{
    __shared__ __align__(16) char smem[2 * 272 * 128];
    char* xs = smem;                  // 272 rows x 64 bf16 (row = t0-1+local)
    char* hs = smem + 272 * 128;      // 272 rows x 64 bf16 (gelu'd stem out)

    const int tid = threadIdx.x, lane = tid & 63, w = tid >> 6;
    const int lr = lane & 15, lk = lane >> 4;       // frag row/col, k-group
    const int ct = w & 3, wh = w >> 2;              // col-tile, row-half
    const int colN = ct * 16 + lr;
    const int b = blockIdx.x >> 4, strip = blockIdx.x & 15, t0 = strip * 256;

    // ---- stage masked x rows [t0-1, t0+256] (locals 0..257; 258..271 zero) ----
    const unsigned short* xb = xc + (size_t)b * 4096 * 64;
    const unsigned char*  mb = mc + (size_t)b * 4096 * 64;
    for (int idx = tid; idx < 272 * 8; idx += 512) {
        const int row = idx >> 3, cc = idx & 7;
        const int t = t0 - 1 + row;
        uint4 xv = {0u, 0u, 0u, 0u};
        if (row < 258 && t >= 0 && t < 4096) {
            const size_t gb = (size_t)t * 64 + cc * 8;
            xv = *(const uint4*)(xb + gb);
            uint2 mv = *(const uint2*)(mb + gb);
            union { uint2 v; unsigned char c[8]; } M; M.v = mv;
            union { uint4 v; unsigned short s[8]; } X; X.v = xv;
#pragma unroll
            for (int j = 0; j < 8; ++j) if (M.c[j]) X.s[j] = 0;
            xv = X.v;
        }
        *(uint4*)(xs + row * 128 + ((cc ^ (row & 7)) << 4)) = xv;
    }

    // ---- B-frags: stem_w (64x64 fp32 -> bf16), lane holds col=colN, k contig ----
    bf16x8 bs[2];
#pragma unroll
    for (int kb = 0; kb < 2; ++kb) {
        bf16x8 f;
#pragma unroll
        for (int j = 0; j < 8; ++j)
            f[j] = (short)f2bf(sw[(size_t)(kb * 32 + lk * 8 + j) * 64 + colN]);
        bs[kb] = f;
    }
    const float sbias = sb[colN];
    // conv B-frags: Bk[i][o] = cw[o*192 + i*3 + k]
    bf16x8 bc[3][2];
#pragma unroll
    for (int k = 0; k < 3; ++k)
#pragma unroll
        for (int kb = 0; kb < 2; ++kb) {
            bf16x8 f;
#pragma unroll
            for (int j = 0; j < 8; ++j)
                f[j] = (short)f2bf(cw[(size_t)colN * 192 + (kb * 32 + lk * 8 + j) * 3 + k]);
            bc[k][kb] = f;
        }
    const float cbias = cb[colN];

    __syncthreads();

    // ---- GEMM1: h = gelu(x @ stem_w + b), 17 row-tiles (272 rows) ----
    for (int rt = wh; rt < 17; rt += 2) {
        const int arow = rt * 16 + lr;
        bf16x8 a0 = *(const bf16x8*)(xs + arow * 128 + (((0 + lk) ^ (arow & 7)) << 4));
        bf16x8 a1 = *(const bf16x8*)(xs + arow * 128 + (((4 + lk) ^ (arow & 7)) << 4));
        f32x4 acc = {0.f, 0.f, 0.f, 0.f};
        acc = __builtin_amdgcn_mfma_f32_16x16x32_bf16(a0, bs[0], acc, 0, 0, 0);
        acc = __builtin_amdgcn_mfma_f32_16x16x32_bf16(a1, bs[1], acc, 0, 0, 0);
#pragma unroll
        for (int j = 0; j < 4; ++j) {
            const int row = rt * 16 + lk * 4 + j;
            if (row < 258) {
                const int t = t0 - 1 + row;
                unsigned short hv = (t >= 0 && t < 4096)
                    ? f2bf(gelu_f(acc[j] + sbias)) : (unsigned short)0;
                *(unsigned short*)(hs + row * 128 +
                    ((((colN >> 3) ^ (row & 7)) << 4)) + (colN & 7) * 2) = hv;
            }
        }
    }
    __syncthreads();

    // ---- GEMM2: out = gelu(sum_k h[t+k-1] @ Wk + cb), 16 out row-tiles ----
    unsigned short* h2b = h2 + ((size_t)b * 4096 + t0) * 64;
    for (int ot = wh; ot < 16; ot += 2) {
        f32x4 acc = {0.f, 0.f, 0.f, 0.f};
#pragma unroll
        for (int k = 0; k < 3; ++k) {
            const int arow = ot * 16 + k + lr;   // h local row = out local + k
            bf16x8 a0 = *(const bf16x8*)(hs + arow * 128 + (((0 + lk) ^ (arow & 7)) << 4));
            bf16x8 a1 = *(const bf16x8*)(hs + arow * 128 + (((4 + lk) ^ (arow & 7)) << 4));
            acc = __builtin_amdgcn_mfma_f32_16x16x32_bf16(a0, bc[k][0], acc, 0, 0, 0);
            acc = __builtin_amdgcn_mfma_f32_16x16x32_bf16(a1, bc[k][1], acc, 0, 0, 0);
        }
#pragma unroll
        for (int j = 0; j < 4; ++j) {
            const int orow = ot * 16 + lk * 4 + j;
            h2b[(size_t)orow * 64 + colN] = f2h_bits(gelu_f(acc[j] + cbias));
        }
    }
}

// ---------------- gx for chunk 0 (standalone, t-split x4, 8-way ILP) --------
__global__ __launch_bounds__(384) void k_gx0(const unsigned short* __restrict__ h2,
    const float* __restrict__ wih, const float* __restrict__ bih,
    const float* __restrict__ bhh, unsigned short* __restrict__ gx0)
{
    const int tid = threadIdx.x, lane = tid & 63, wav = tid >> 6; // 6 waves
    const int col = wav * 64 + lane;
    half2v wg[32];
#pragma unroll
    for (int i = 0; i < 32; ++i)
        wg[i] = half2v{(_Float16)wih[(size_t)col * 64 + 2 * i],
                       (_Float16)wih[(size_t)col * 64 + 2 * i + 1]};
    const float gb = bih[col] + (col < 256 ? bhh[col] : 0.f);
    const unsigned int* h232 = (const unsigned int*)h2;
    const int b = blockIdx.x >> 2, th = (blockIdx.x & 3) * 128;
    const size_t hb = (size_t)b * 4096 * 32;
    unsigned int hw[8], hn[8];
#pragma unroll
    for (int s = 0; s < 8; ++s)
        hw[s] = h232[hb + (size_t)(th + s) * 32 + (lane & 31)];
    for (int t = th; t < th + 128; t += 8) {
#pragma unroll
        for (int s = 0; s < 8; ++s) {
            const int tt = t + 8 + s;
            hn[s] = (tt < th + 128) ? h232[hb + (size_t)tt * 32 + (lane & 31)] : 0u;
        }
        float ss[8] = {0.f, 0.f, 0.f, 0.f, 0.f, 0.f, 0.f, 0.f};
#pragma unroll
        for (int i = 0; i < 32; ++i) {
#pragma unroll
            for (int s = 0; s < 8; ++s)
                ss[s] = dot2(u2h2(rlu(hw[s], i)), wg[i], ss[s]);
        }
#pragma unroll
        for (int s = 0; s < 8; ++s)
            gx0[((size_t)b * CHUNK + t + s) * 384 + col] = f2h_bits(ss[s] + gb);
#pragma unroll
        for (int s = 0; s < 8; ++s) hw[s] = hn[s];
    }
}

// ---------------- head helpers (512 threads = 8 waves) ----------------
DEV void head_layer(const unsigned short* __restrict__ in,
                    unsigned short* __restrict__ out,
                    const float* __restrict__ w, const float* __restrict__ bias,
                    int hb, int nb)
{
    const int tid = threadIdx.x, lane = tid & 63, wav = tid >> 6;
    const int tm = wav >> 1, cs = wav & 1;            // 4 row-slots x 2 col-halves
    const int col = cs * 64 + lane;
    half2v wv[64];
#pragma unroll
    for (int i = 0; i < 64; ++i)
        wv[i] = half2v{(_Float16)w[(size_t)(2 * i) * 128 + col],
                       (_Float16)w[(size_t)(2 * i + 1) * 128 + col]};
    const float bb = bias[col];
    for (int r = hb * 4 + tm; r < 64 * CHUNK; r += nb * 4) {
        const unsigned int* ir = (const unsigned int*)(in + (size_t)r * 128);
        unsigned int zw = ir[lane];       // pairs (z[2lane], z[2lane+1])
        float a0 = 0.f, a1 = 0.f;
#pragma unroll
        for (int i = 0; i < 64; i += 2) {
            a0 = dot2(u2h2(rlu(zw, i)),     wv[i],     a0);
            a1 = dot2(u2h2(rlu(zw, i + 1)), wv[i + 1], a1);
        }
        out[(size_t)r * 128 + col] = f2h_bits(gelu_f(a0 + a1 + bb));
    }
}

DEV void head3_layer(const unsigned short* __restrict__ in,
                     const float* __restrict__ w, const float* __restrict__ bias,
                     const unsigned short* __restrict__ xc,
                     const unsigned char* __restrict__ mc,
                     const float* __restrict__ inv2, double* __restrict__ lossacc,
                     int hb, int nb, int hc)
{
    const int tid = threadIdx.x, lane = tid & 63, wav = tid >> 6;
    half2v wv[64];
#pragma unroll
    for (int i = 0; i < 64; ++i)
        wv[i] = half2v{(_Float16)w[(size_t)(2 * i) * 64 + lane],
                       (_Float16)w[(size_t)(2 * i + 1) * 64 + lane]};
    const float bb = bias[lane];
    const float iv = inv2[lane];
    float accf = 0.f; double acc = 0.0; int spill = 0;
    for (int r = hb * 8 + wav; r < 64 * CHUNK; r += nb * 8) {
        const unsigned int* ir = (const unsigned int*)(in + (size_t)r * 128);
        unsigned int zw = ir[lane];
        float a0 = 0.f, a1 = 0.f;
#pragma unroll
        for (int i = 0; i < 64; i += 2) {
            a0 = dot2(u2h2(rlu(zw, i)),     wv[i],     a0);
            a1 = dot2(u2h2(rlu(zw, i + 1)), wv[i + 1], a1);
        }
        float xr = a0 + a1 + bb;
        const int bidx = r >> 9, tl = r & (CHUNK - 1);
        const int t = hc * CHUNK + tl;
        const size_t xb = ((size_t)bidx * 4096 + t) * 64 + lane;
        float dd = xr - bf2f(xc[xb]);
        accf += mc[xb] ? dd * dd * iv : 0.f;
        if (++spill == 64) { acc += (double)accf; accf = 0.f; spill = 0; }
    }
    acc += (double)accf;
    __shared__ double red[512];
    red[tid] = acc;
    __syncthreads();
    for (int s = 256; s > 0; s >>= 1) {
        if (tid < s) red[tid] += red[tid + s];
        __syncthreads();
    }
    if (tid == 0) atomicAdd(lossacc, red[0]);
}

// ---------------- pipelined chunk launch ----------------
// GRU role: R4/R6 one-barrier register-h structure + ASM-PINNED weights.
// The structure twice lost ONLY to regalloc sinking the 48 weight loads
// into the loop (VGPR=68, FETCH +4.4GB). asm("" : "+v"(w)) makes each
// loaded weight opaque -- the compiler cannot re-materialize it from
// memory, forcing residency. (512,2) gives the 256-VGPR budget.
// Race-free: B(t)'s ds_reads of parity p drain at bar(t+1) (lgkmcnt(0))
// before any wave's A(t+2) rewrites parity p.
__global__ __launch_bounds__(512, 2) void k_pipe(int c,
    unsigned short* __restrict__ gxring, const unsigned short* __restrict__ h2,
    const float* __restrict__ wih, const float* __restrict__ bih,
    const float* __restrict__ whh, const float* __restrict__ bhh,
    unsigned short* __restrict__ zring, unsigned short* __restrict__ r1ring,
    unsigned short* __restrict__ r2ring, float* __restrict__ hstate,
    const float* __restrict__ h1w, const float* __restrict__ h1b,
    const float* __restrict__ h2w, const float* __restrict__ h2b,
    const float* __restrict__ h3w, const float* __restrict__ h3b,
    const unsigned short* __restrict__ xc, const unsigned char* __restrict__ mc,
    const float* __restrict__ inv2, double* __restrict__ lossacc)
{
    const int tid = threadIdx.x, lane = tid & 63, wav = tid >> 6;

    const int nGru = (c < NCHUNK) ? 64 : 0;
    const int nGx  = (c + 1 < NCHUNK) ? 64 : 0;
    const bool h1On = (c >= 1 && c - 1 < NCHUNK);
    const bool h2On = (c >= 2 && c - 2 < NCHUNK);
    const bool h3On = (c >= 3 && c - 3 < NCHUNK);
    const int rem = 256 - nGru - nGx;
    const int w1 = h1On ? 3 : 0, w2 = h2On ? 3 : 0, w3 = h3On ? 2 : 0;
    const int wsum = w1 + w2 + w3;
    const int n1 = wsum ? rem * w1 / wsum : 0;
    const int n2 = wsum ? rem * w2 / wsum : 0;
    const int n3 = h3On ? rem - n1 - n2 : 0;

    int bid = (int)blockIdx.x;

    if (bid < nGru) {
        // -------- GRU role: 1 batch/block, 1 barrier/step, register h --------
        __shared__ float part[2][4][3][128];   // [parity][ksw][gate][dim]
        const int b = bid;
        const int half = wav & 1, ksw = wav >> 1;
        const int d = half * 64 + lane;
        const int kb = __builtin_amdgcn_readfirstlane(ksw * 16);
        const unsigned short* gxb = gxring + (size_t)(c & 1) * GXCH + (size_t)b * CHUNK * 384;
        unsigned short* zc = zring + (size_t)(c & 1) * RCH + (size_t)b * CHUNK * 128;
        const unsigned int* gx32 = (const unsigned int*)gxb;

        half2v wr[16], wz[16], wn[16];
#pragma unroll
        for (int i = 0; i < 16; ++i) {
            const int k0 = ksw * 32 + 2 * i;
            wr[i] = half2v{(_Float16)whh[(size_t)d * 128 + k0],
                           (_Float16)whh[(size_t)d * 128 + k0 + 1]};
            wz[i] = half2v{(_Float16)whh[(size_t)(128 + d) * 128 + k0],
                           (_Float16)whh[(size_t)(128 + d) * 128 + k0 + 1]};
            wn[i] = half2v{(_Float16)whh[(size_t)(256 + d) * 128 + k0],
                           (_Float16)whh[(size_t)(256 + d) * 128 + k0 + 1]};
        }
        // PIN: make each weight value opaque so regalloc cannot sink the
        // loads into the serial loop (the R4/R6 failure mode).
#pragma unroll
        for (int i = 0; i < 16; ++i) {
            asm volatile("" : "+v"(wr[i]));
            asm volatile("" : "+v"(wz[i]));
            asm volatile("" : "+v"(wn[i]));
        }
        const float bhn0 = bhh[256 + 2 * lane];
        const float bhn1 = bhh[256 + 2 * lane + 1];

        float h0 = 0.f, h1v = 0.f;
        if (c > 0) {
            float2 hv = *(const float2*)(hstate + b * 128 + 2 * lane);
            h0 = hv.x; h1v = hv.y;
        }
        unsigned int hw = (unsigned int)f2h_bits(h0) | ((unsigned int)f2h_bits(h1v) << 16);

        // gx prefetch: u32 pair (2*lane, 2*lane+1) per gate, 4-step blocks.
        // All waves load the SAME addresses -> L1 broadcast.
        unsigned int cur[12], nxt[12];
#pragma unroll
        for (int s = 0; s < 4; ++s)
#pragma unroll
            for (int g = 0; g < 3; ++g) {
                cur[s * 3 + g] = gx32[(size_t)s * 192 + g * 64 + lane];
                nxt[s * 3 + g] = gx32[(size_t)(4 + s) * 192 + g * 64 + lane];
            }

        int p = 0;
        for (int tb = 0; tb < CHUNK / 4; ++tb) {
#pragma unroll
            for (int ti = 0; ti < 4; ++ti) {
                // phase A: k-slice matvec from register h
                float sr = 0.f, sz = 0.f, sn = 0.f;
#pragma unroll
                for (int i = 0; i < 16; ++i) {
                    const half2v hp = u2h2(rlu(hw, kb + i));
                    sr = dot2(hp, wr[i], sr);
                    sz = dot2(hp, wz[i], sz);
                    sn = dot2(hp, wn[i], sn);
                }
                part[p][ksw][0][d] = sr;
                part[p][ksw][1][d] = sz;
                part[p][ksw][2][d] = sn;
                bar_lds();
                // phase B: redundant gate update on ALL waves for pair (2l,2l+1)
                const float2 r0v = ((const float2*)part[p][0][0])[lane];
                const float2 r1v = ((const float2*)part[p][1][0])[lane];
                const float2 r2v = ((const float2*)part[p][2][0])[lane];
                const float2 r3v = ((const float2*)part[p][3][0])[lane];
                const float2 z0v = ((const float2*)part[p][0][1])[lane];
                const float2 z1v = ((const float2*)part[p][1][1])[lane];
                const float2 z2v = ((const float2*)part[p][2][1])[lane];
                const float2 z3v = ((const float2*)part[p][3][1])[lane];
                const float2 n0v = ((const float2*)part[p][0][2])[lane];
                const float2 n1v = ((const float2*)part[p][1][2])[lane];
                const float2 n2v = ((const float2*)part[p][2][2])[lane];
                const float2 n3v = ((const float2*)part[p][3][2])[lane];
                const half2v cr = u2h2(cur[ti * 3 + 0]);
                const half2v cz = u2h2(cur[ti * 3 + 1]);
                const half2v cn = u2h2(cur[ti * 3 + 2]);
                const float gr0 = (r0v.x + r1v.x) + (r2v.x + r3v.x) + (float)cr.x;
                const float gr1 = (r0v.y + r1v.y) + (r2v.y + r3v.y) + (float)cr.y;
                const float gz0 = (z0v.x + z1v.x) + (z2v.x + z3v.x) + (float)cz.x;
                const float gz1 = (z0v.y + z1v.y) + (z2v.y + z3v.y) + (float)cz.y;
                const float gn0 = (n0v.x + n1v.x) + (n2v.x + n3v.x) + bhn0;
                const float gn1 = (n0v.y + n1v.y) + (n2v.y + n3v.y) + bhn1;
                const float rr0 = sigm_f(gr0), rr1 = sigm_f(gr1);
                const float zz0 = sigm_f(gz0), zz1 = sigm_f(gz1);
                const float nn0 = tanh_f((float)cn.x + rr0 * gn0);
                const float nn1 = tanh_f((float)cn.y + rr1 * gn1);
                h0  = nn0 + zz0 * (h0 - nn0);
                h1v = nn1 + zz1 * (h1v - nn1);
                hw = (unsigned int)f2h_bits(h0) | ((unsigned int)f2h_bits(h1v) << 16);
                if (wav == 0)
                    *(unsigned int*)(zc + (size_t)(tb * 4 + ti) * 128 + 2 * lane) = hw;
                p ^= 1;
            }
#pragma unroll
            for (int j = 0; j < 12; ++j) cur[j] = nxt[j];
            const int tnb = (tb + 2 <= CHUNK / 4 - 1) ? (tb + 2) * 4 : (CHUNK - 4);
#pragma unroll
            for (int s = 0; s < 4; ++s)
#pragma unroll
                for (int g = 0; g < 3; ++g)
                    nxt[s * 3 + g] = gx32[(size_t)(tnb + s) * 192 + g * 64 + lane];
        }
        if (wav == 0) {
            float2 hv; hv.x = h0; hv.y = h1v;
            *(float2*)(hstate + b * 128 + 2 * lane) = hv;
        }
        return;
    }
    bid -= nGru;

    if (bid < nGx) {
        // -------- gx role for chunk c+1 (8-way ILP, no serial dep) --------
        if (wav >= 6) return;
        const int b = bid;
        unsigned short* gxd = gxring + (size_t)((c + 1) & 1) * GXCH + (size_t)b * CHUNK * 384;
        const int col = wav * 64 + lane;
        half2v wg[32];
#pragma unroll
        for (int i = 0; i < 32; ++i)
            wg[i] = half2v{(_Float16)wih[(size_t)col * 64 + 2 * i],
                           (_Float16)wih[(size_t)col * 64 + 2 * i + 1]};
        const float gb = bih[col] + (col < 256 ? bhh[col] : 0.f);
        const unsigned int* h232 = (const unsigned int*)h2;
        const size_t hb = ((size_t)b * 4096 + (size_t)(c + 1) * CHUNK) * 32;
        unsigned int hw[8], hn[8];
#pragma unroll
        for (int s = 0; s < 8; ++s)
            hw[s] = h232[hb + (size_t)s * 32 + (lane & 31)];
        for (int t = 0; t < CHUNK; t += 8) {
#pragma unroll
            for (int s = 0; s < 8; ++s) {
                const int tt = t + 8 + s;
                hn[s] = (tt < CHUNK) ? h232[hb + (size_t)tt * 32 + (lane & 31)] : 0u;
            }
            float ss[8] = {0.f, 0.f, 0.f, 0.f, 0.f, 0.f, 0.f, 0.f};
#pragma unroll
            for (int i = 0; i < 32; ++i) {
#pragma unroll
                for (int s = 0; s < 8; ++s)
                    ss[s] = dot2(u2h2(rlu(hw[s], i)), wg[i], ss[s]);
            }
#pragma unroll
            for (int s = 0; s < 8; ++s)
                gxd[(size_t)(t + s) * 384 + col] = f2h_bits(ss[s] + gb);
#pragma unroll
            for (int s = 0; s < 8; ++s) hw[s] = hn[s];
        }
        return;
    }
    bid -= nGx;

    // ---------------- head roles ----------------
    if (bid < n1) {
        const int hc = c - 1;
        head_layer(zring + (size_t)(hc & 1) * RCH, r1ring + (size_t)(hc & 1) * RCH,
                   h1w, h1b, bid, n1);
        return;
    }
    bid -= n1;
    if (bid < n2) {
        const int hc = c - 2;
        head_layer(r1ring + (size_t)(hc & 1) * RCH, r2ring + (size_t)(hc & 1) * RCH,
                   h2w, h2b, bid, n2);
        return;
    }
    bid -= n2;
    if (bid < n3) {
        const int hc = c - 3;
        head3_layer(r2ring + (size_t)(hc & 1) * RCH, h3w, h3b, xc, mc, inv2,
                    lossacc, bid, n3, hc);
    }
}

__global__ void k_loss(const double* __restrict__ acc, const int* __restrict__ flags,
                       void* __restrict__ out)
{
    double cnt = acc[128];
    double denom = (cnt < 1.0) ? 1.0 : cnt;
    float v = (float)(acc[129] / denom);
    if (flags[0] == 1) ((float*)out)[0] = v;
    else ((unsigned short*)out)[0] = f2bf(v);
}

extern "C" void kernel_launch(void* const* d_in, const int* in_sizes, int n_in,
                              void* d_out, int out_size, void* d_ws, size_t ws_size,
                              hipStream_t stream)
{
    (void)in_sizes; (void)n_in; (void)out_size; (void)ws_size;
    const void* x    = d_in[0];
    const void* mask = d_in[1];

    char* ws = (char*)d_ws;
    unsigned short* xc   = (unsigned short*)(ws + OFF_XC);
    unsigned char*  mc   = (unsigned char*)(ws + OFF_MC);
    float*          wc   = (float*)(ws + OFF_WC);
    double*         acc  = (double*)(ws + OFF_ACC);
    int*            cnt  = (int*)(ws + OFF_ACC + 1056);
    int*            flg  = (int*)(ws + OFF_ACC + 1088);
    float*          inv2 = (float*)(ws + OFF_ACC + 1216);
    unsigned short* h2   = (unsigned short*)(ws + OFF_H2);
    unsigned short* gxr  = (unsigned short*)(ws + OFF_GX);
    unsigned short* zr   = (unsigned short*)(ws + OFF_ZR);
    unsigned short* r1r  = (unsigned short*)(ws + OFF_R1);
    unsigned short* r2r  = (unsigned short*)(ws + OFF_R2);
    float*          hst  = (float*)(ws + OFF_HST);

    const float* stem_w = wc + 0;
    const float* stem_b = wc + 4096;
    const float* conv_w = wc + 4160;
    const float* conv_b = wc + 16448;
    const float* w_ih   = wc + 16512;
    const float* w_hh   = wc + 41088;
    const float* b_ih   = wc + 90240;
    const float* b_hh   = wc + 90624;
    const float* h1_w   = wc + 91008;
    const float* h1_b   = wc + 107392;
    const float* h2_w   = wc + 107520;
    const float* h2_b   = wc + 123904;
    const float* h3_w   = wc + 124032;
    const float* h3_b   = wc + 132224;

    hipMemsetAsync(ws + OFF_ACC, 0, 4096, stream);
    k_probe   <<<256, 256, 0, stream>>>((const unsigned short*)x, (const unsigned char*)mask, cnt);
    k_classify<<<1, 1, 0, stream>>>(cnt, flg);
    k_canon_x <<<8192, 256, 0, stream>>>(x, mask, xc, mc, flg);
    k_canon_w <<<14, 256, 0, stream>>>(d_in[2], d_in[3], d_in[4], d_in[5], d_in[6],
                                       d_in[7], d_in[8], d_in[9], d_in[10], d_in[11],
                                       d_in[12], d_in[13], d_in[14], d_in[15], wc, flg);
    k_std     <<<512, 256, 0, stream>>>(xc, mc, acc);
    k_scale   <<<1, 64, 0, stream>>>(acc, inv2);
    k_stemconv<<<1024, 512, 0, stream>>>(xc, mc, stem_w, stem_b, conv_w, conv_b, h2);
    k_gx0     <<<256, 384, 0, stream>>>(h2, w_ih, b_ih, b_hh, gxr);

    for (int c = 0; c < NCHUNK + 3; ++c) {
        k_pipe<<<256, 512, 0, stream>>>(
            c, gxr, h2, w_ih, b_ih, w_hh, b_hh,
            zr, r1r, r2r, hst, h1_w, h1_b, h2_w, h2_b, h3_w, h3_b,
            xc, mc, inv2, acc + 129);
    }
    k_loss<<<1, 1, 0, stream>>>(acc, flg, d_out);
}

// Round 9
// 4986.177 us; speedup vs baseline: 1.0090x; 1.0090x over previous
//
#include <hip/hip_runtime.h>
#include <hip/hip_bf16.h>

#define DEV __device__ __forceinline__

namespace {

constexpr int ROWS = 64 * 4096;        // B*T
constexpr int NE   = ROWS * 64;        // B*T*F
constexpr int CHUNK = 512;
constexpr int NCHUNK = 4096 / CHUNK;   // 8

constexpr size_t GXCH = (size_t)64 * CHUNK * 384;   // elems per gx chunk buf
constexpr size_t RCH  = (size_t)64 * CHUNK * 128;   // elems per z/r1/r2 chunk buf

// workspace layout (bytes), total ~185.1 MB
constexpr size_t OFF_XC  = 0;            // bf16 NE          33,554,432
constexpr size_t OFF_MC  = 33554432;     // u8 NE            16,777,216
constexpr size_t OFF_WC  = 50331648;     // fp32 weights
constexpr size_t OFF_ACC = 50862080;     // 4 KB acc/flags
constexpr size_t OFF_H2  = 50866176;     // f16 NE           33,554,432
constexpr size_t OFF_GX  = 84420608;     // f16 2*GXCH       50,331,648
constexpr size_t OFF_ZR  = 134752256;    // f16 2*RCH        16,777,216
constexpr size_t OFF_R1  = 151529472;    // f16 2*RCH
constexpr size_t OFF_R2  = 168306688;    // f16 2*RCH
constexpr size_t OFF_HST = 185083904;    // fp32 64*128

DEV float rlane(float v, int l) {
    return __int_as_float(__builtin_amdgcn_readlane(__float_as_int(v), l));
}
DEV unsigned int rlu(unsigned int v, int l) {
    return (unsigned int)__builtin_amdgcn_readlane((int)v, l);
}
DEV float bf2f(unsigned short u) { return __uint_as_float(((unsigned int)u) << 16); }
DEV unsigned short f2bf(float f) {
    unsigned int u = __float_as_uint(f);
    unsigned int r = (u + 0x7FFFu + ((u >> 16) & 1u)) >> 16;
    return (unsigned short)r;
}
DEV float gelu_f(float v) { return 0.5f * v * (1.0f + erff(v * 0.70710678118654752f)); }
DEV float sigm_f(float x) { return 1.0f / (1.0f + __expf(-x)); }
DEV float tanh_f(float x) { float t = __expf(2.0f * x); return 1.0f - 2.0f / (t + 1.0f); }

typedef _Float16 half2v __attribute__((ext_vector_type(2)));
typedef __attribute__((ext_vector_type(8))) short bf16x8;
typedef __attribute__((ext_vector_type(4))) float f32x4;

DEV float dot2(half2v a, half2v b, float c) {
#if __has_builtin(__builtin_amdgcn_fdot2)
    return __builtin_amdgcn_fdot2(a, b, c, false);
#else
    return c + (float)a.x * (float)b.x + (float)a.y * (float)b.y;
#endif
}
DEV unsigned short f2h_bits(float f) {
    return __builtin_bit_cast(unsigned short, (_Float16)f);
}
DEV float h2f_bits(unsigned short u) {
    return (float)__builtin_bit_cast(_Float16, u);
}
DEV half2v u2h2(unsigned int p) { return __builtin_bit_cast(half2v, p); }
// LDS-only barrier: skips the vmcnt(0) drain __syncthreads would emit.
DEV void bar_lds() {
    asm volatile("s_waitcnt lgkmcnt(0)\n\ts_barrier" ::: "memory");
}

} // namespace

// ---------------- dtype probe (memory-safe) ----------------
__global__ __launch_bounds__(256) void k_probe(const unsigned short* __restrict__ xh,
    const unsigned char* __restrict__ mb, int* __restrict__ cnt)
{
    const int g = blockIdx.x * 256 + threadIdx.x;
    int hit = 0;
    for (int i = g; i < (1 << 20); i += (1 << 16)) {
        int tb = (xh[i] >> 8) & 0x7F;
        hit += (tb >= 0x3C && tb <= 0x40) ? 1 : 0;
    }
    int a = 0, b = 0, c = 0, d = 0;
    for (int i = g; i < (1 << 24); i += (1 << 16)) {
        unsigned char v = mb[i];
        int r = i & 3;
        a += (v == 1    && r == 0) ? 1 : 0;
        b += (v == 1    && r != 0) ? 1 : 0;
        c += (v == 0x80 && r == 0) ? 1 : 0;
        d += (v == 0x80 && r == 2) ? 1 : 0;
    }
    __shared__ int sm[256];
    int vals[5] = {hit, a, b, c, d};
#pragma unroll
    for (int k = 0; k < 5; ++k) {
        sm[threadIdx.x] = vals[k];
        __syncthreads();
        for (int s = 128; s > 0; s >>= 1) {
            if (threadIdx.x < s) sm[threadIdx.x] += sm[threadIdx.x + s];
            __syncthreads();
        }
        if (threadIdx.x == 0) atomicAdd(cnt + k, sm[0]);
        __syncthreads();
    }
}

__global__ void k_classify(const int* __restrict__ cnt, int* __restrict__ flags)
{
    flags[0] = (cnt[0] > 786432) ? 0 : 1;
    int fm;
    if (cnt[2] > 0) fm = 0;
    else if (cnt[1] > 0) fm = 1;
    else if (cnt[3] > 0) fm = 2;
    else if (cnt[4] > 0) fm = 3;
    else fm = 0;
    flags[1] = fm;
}

// ---------------- canonicalize x (bf16) + mask (u8) ----------------
__global__ __launch_bounds__(256) void k_canon_x(const void* __restrict__ x,
    const void* __restrict__ mask, unsigned short* __restrict__ xc,
    unsigned char* __restrict__ mc, const int* __restrict__ flags)
{
    const int fF = flags[0], fM = flags[1];
    for (int i = blockIdx.x * 256 + threadIdx.x; i < NE; i += gridDim.x * 256) {
        unsigned short h;
        if (fF == 0) h = ((const unsigned short*)x)[i];
        else         h = f2bf(((const float*)x)[i]);
        xc[i] = h;
        unsigned char m;
        if (fM == 0)      m = (((const unsigned char*)mask)[i]  != 0) ? 1 : 0;
        else if (fM == 1) m = (((const int*)mask)[i]            != 0) ? 1 : 0;
        else if (fM == 2) m = (((const unsigned short*)mask)[i] != 0) ? 1 : 0;
        else              m = (((const unsigned int*)mask)[i]   != 0) ? 1 : 0;
        mc[i] = m;
    }
}

// ---------------- canonicalize weights to fp32 ----------------
__global__ __launch_bounds__(256) void k_canon_w(
    const void* p0, const void* p1, const void* p2, const void* p3,
    const void* p4, const void* p5, const void* p6, const void* p7,
    const void* p8, const void* p9, const void* p10, const void* p11,
    const void* p12, const void* p13, float* __restrict__ wc,
    const int* __restrict__ flags)
{
    const int fF = flags[0];
    const void* p; int off, n;
    switch (blockIdx.x) {
        case 0:  p = p0;  off = 0;      n = 4096;  break;  // stem_w
        case 1:  p = p1;  off = 4096;   n = 64;    break;  // stem_b
        case 2:  p = p2;  off = 4160;   n = 12288; break;  // conv_w
        case 3:  p = p3;  off = 16448;  n = 64;    break;  // conv_b
        case 4:  p = p4;  off = 16512;  n = 24576; break;  // w_ih
        case 5:  p = p5;  off = 41088;  n = 49152; break;  // w_hh
        case 6:  p = p6;  off = 90240;  n = 384;   break;  // b_ih
        case 7:  p = p7;  off = 90624;  n = 384;   break;  // b_hh
        case 8:  p = p8;  off = 91008;  n = 16384; break;  // h1_w
        case 9:  p = p9;  off = 107392; n = 128;   break;  // h1_b
        case 10: p = p10; off = 107520; n = 16384; break;  // h2_w
        case 11: p = p11; off = 123904; n = 128;   break;  // h2_b
        case 12: p = p12; off = 124032; n = 8192;  break;  // h3_w
        default: p = p13; off = 132224; n = 64;    break;  // h3_b
    }
    for (int i = threadIdx.x; i < n; i += 256) {
        float v = (fF == 0) ? bf2f(((const unsigned short*)p)[i]) : ((const float*)p)[i];
        wc[off + i] = v;
    }
}

// ---------------- std over features + mask count ----------------
__global__ __launch_bounds__(256) void k_std(const unsigned short* __restrict__ xc,
    const unsigned char* __restrict__ mc, double* __restrict__ acc)
{
    const int tid = threadIdx.x, f = tid & 63, slot = tid >> 6;
    float s = 0.f, sq = 0.f; int cnt = 0;
    for (int row = blockIdx.x * 4 + slot; row < ROWS; row += gridDim.x * 4) {
        const size_t base = (size_t)row * 64 + f;
        float v = bf2f(xc[base]);
        s += v; sq += v * v;
        cnt += mc[base];
    }
    __shared__ float ls[256], lq[256];
    __shared__ int lc[256];
    ls[tid] = s; lq[tid] = sq; lc[tid] = cnt;
    __syncthreads();
    if (tid < 64) {
        float S = ls[tid] + ls[tid + 64] + ls[tid + 128] + ls[tid + 192];
        float Q = lq[tid] + lq[tid + 64] + lq[tid + 128] + lq[tid + 192];
        atomicAdd(acc + tid, (double)S);
        atomicAdd(acc + 64 + tid, (double)Q);
    }
    if (tid == 0) {
        int tot = 0;
        for (int i = 0; i < 256; ++i) tot += lc[i];
        atomicAdd(acc + 128, (double)tot);
    }
}

__global__ void k_scale(const double* __restrict__ acc, float* __restrict__ inv2)
{
    int f = threadIdx.x;
    const double N = (double)ROWS;
    double sum = acc[f], sq = acc[64 + f];
    double var = (sq - sum * sum / N) / (N - 1.0);
    double sd = sqrt(var) + 1e-8;
    inv2[f] = (float)(1.0 / (sd * sd));
}

// ---------------- fused stem + conv via MFMA ----------------
__global__ __launch_bounds__(512) void k_stemconv(const unsigned short* __restrict__ xc,
    const unsigned char* __restrict__ mc, const float* __restrict__ sw,
    const float* __restrict__ sb, const float* __restrict__ cw,
    const float* __restrict__ cb, unsigned short* __restrict__ h2)
{
    __shared__ __align__(16) char smem[2 * 272 * 128];
    char* xs = smem;                  // 272 rows x 64 bf16 (row = t0-1+local)
    char* hs = smem + 272 * 128;      // 272 rows x 64 bf16 (gelu'd stem out)

    const int tid = threadIdx.x, lane = tid & 63, w = tid >> 6;
    const int lr = lane & 15, lk = lane >> 4;       // frag row/col, k-group
    const int ct = w & 3, wh = w >> 2;              // col-tile, row-half
    const int colN = ct * 16 + lr;
    const int b = blockIdx.x >> 4, strip = blockIdx.x & 15, t0 = strip * 256;

    // ---- stage masked x rows [t0-1, t0+256] (locals 0..257; 258..271 zero) ----
    const unsigned short* xb = xc + (size_t)b * 4096 * 64;
    const unsigned char*  mb = mc + (size_t)b * 4096 * 64;
    for (int idx = tid; idx < 272 * 8; idx += 512) {
        const int row = idx >> 3, cc = idx & 7;
        const int t = t0 - 1 + row;
        uint4 xv = {0u, 0u, 0u, 0u};
        if (row < 258 && t >= 0 && t < 4096) {
            const size_t gb = (size_t)t * 64 + cc * 8;
            xv = *(const uint4*)(xb + gb);
            uint2 mv = *(const uint2*)(mb + gb);
            union { uint2 v; unsigned char c[8]; } M; M.v = mv;
            union { uint4 v; unsigned short s[8]; } X; X.v = xv;
#pragma unroll
            for (int j = 0; j < 8; ++j) if (M.c[j]) X.s[j] = 0;
            xv = X.v;
        }
        *(uint4*)(xs + row * 128 + ((cc ^ (row & 7)) << 4)) = xv;
    }

    // ---- B-frags: stem_w (64x64 fp32 -> bf16), lane holds col=colN, k contig ----
    bf16x8 bs[2];
#pragma unroll
    for (int kb = 0; kb < 2; ++kb) {
        bf16x8 f;
#pragma unroll
        for (int j = 0; j < 8; ++j)
            f[j] = (short)f2bf(sw[(size_t)(kb * 32 + lk * 8 + j) * 64 + colN]);
        bs[kb] = f;
    }
    const float sbias = sb[colN];
    // conv B-frags: Bk[i][o] = cw[o*192 + i*3 + k]
    bf16x8 bc[3][2];
#pragma unroll
    for (int k = 0; k < 3; ++k)
#pragma unroll
        for (int kb = 0; kb < 2; ++kb) {
            bf16x8 f;
#pragma unroll
            for (int j = 0; j < 8; ++j)
                f[j] = (short)f2bf(cw[(size_t)colN * 192 + (kb * 32 + lk * 8 + j) * 3 + k]);
            bc[k][kb] = f;
        }
    const float cbias = cb[colN];

    __syncthreads();

    // ---- GEMM1: h = gelu(x @ stem_w + b), 17 row-tiles (272 rows) ----
    for (int rt = wh; rt < 17; rt += 2) {
        const int arow = rt * 16 + lr;
        bf16x8 a0 = *(const bf16x8*)(xs + arow * 128 + (((0 + lk) ^ (arow & 7)) << 4));
        bf16x8 a1 = *(const bf16x8*)(xs + arow * 128 + (((4 + lk) ^ (arow & 7)) << 4));
        f32x4 acc = {0.f, 0.f, 0.f, 0.f};
        acc = __builtin_amdgcn_mfma_f32_16x16x32_bf16(a0, bs[0], acc, 0, 0, 0);
        acc = __builtin_amdgcn_mfma_f32_16x16x32_bf16(a1, bs[1], acc, 0, 0, 0);
#pragma unroll
        for (int j = 0; j < 4; ++j) {
            const int row = rt * 16 + lk * 4 + j;
            if (row < 258) {
                const int t = t0 - 1 + row;
                unsigned short hv = (t >= 0 && t < 4096)
                    ? f2bf(gelu_f(acc[j] + sbias)) : (unsigned short)0;
                *(unsigned short*)(hs + row * 128 +
                    ((((colN >> 3) ^ (row & 7)) << 4)) + (colN & 7) * 2) = hv;
            }
        }
    }
    __syncthreads();

    // ---- GEMM2: out = gelu(sum_k h[t+k-1] @ Wk + cb), 16 out row-tiles ----
    unsigned short* h2b = h2 + ((size_t)b * 4096 + t0) * 64;
    for (int ot = wh; ot < 16; ot += 2) {
        f32x4 acc = {0.f, 0.f, 0.f, 0.f};
#pragma unroll
        for (int k = 0; k < 3; ++k) {
            const int arow = ot * 16 + k + lr;   // h local row = out local + k
            bf16x8 a0 = *(const bf16x8*)(hs + arow * 128 + (((0 + lk) ^ (arow & 7)) << 4));
            bf16x8 a1 = *(const bf16x8*)(hs + arow * 128 + (((4 + lk) ^ (arow & 7)) << 4));
            acc = __builtin_amdgcn_mfma_f32_16x16x32_bf16(a0, bc[k][0], acc, 0, 0, 0);
            acc = __builtin_amdgcn_mfma_f32_16x16x32_bf16(a1, bc[k][1], acc, 0, 0, 0);
        }
#pragma unroll
        for (int j = 0; j < 4; ++j) {
            const int orow = ot * 16 + lk * 4 + j;
            h2b[(size_t)orow * 64 + colN] = f2h_bits(gelu_f(acc[j] + cbias));
        }
    }
}

// ---------------- gx for chunk 0 (standalone, t-split x4, 8-way ILP) --------
__global__ __launch_bounds__(384) void k_gx0(const unsigned short* __restrict__ h2,
    const float* __restrict__ wih, const float* __restrict__ bih,
    const float* __restrict__ bhh, unsigned short* __restrict__ gx0)
{
    const int tid = threadIdx.x, lane = tid & 63, wav = tid >> 6; // 6 waves
    const int col = wav * 64 + lane;
    half2v wg[32];
#pragma unroll
    for (int i = 0; i < 32; ++i)
        wg[i] = half2v{(_Float16)wih[(size_t)col * 64 + 2 * i],
                       (_Float16)wih[(size_t)col * 64 + 2 * i + 1]};
    const float gb = bih[col] + (col < 256 ? bhh[col] : 0.f);
    const unsigned int* h232 = (const unsigned int*)h2;
    const int b = blockIdx.x >> 2, th = (blockIdx.x & 3) * 128;
    const size_t hb = (size_t)b * 4096 * 32;
    unsigned int hw[8], hn[8];
#pragma unroll
    for (int s = 0; s < 8; ++s)
        hw[s] = h232[hb + (size_t)(th + s) * 32 + (lane & 31)];
    for (int t = th; t < th + 128; t += 8) {
#pragma unroll
        for (int s = 0; s < 8; ++s) {
            const int tt = t + 8 + s;
            hn[s] = (tt < th + 128) ? h232[hb + (size_t)tt * 32 + (lane & 31)] : 0u;
        }
        float ss[8] = {0.f, 0.f, 0.f, 0.f, 0.f, 0.f, 0.f, 0.f};
#pragma unroll
        for (int i = 0; i < 32; ++i) {
#pragma unroll
            for (int s = 0; s < 8; ++s)
                ss[s] = dot2(u2h2(rlu(hw[s], i)), wg[i], ss[s]);
        }
#pragma unroll
        for (int s = 0; s < 8; ++s)
            gx0[((size_t)b * CHUNK + t + s) * 384 + col] = f2h_bits(ss[s] + gb);
#pragma unroll
        for (int s = 0; s < 8; ++s) hw[s] = hn[s];
    }
}

// ---------------- head helpers (512 threads = 8 waves) ----------------
DEV void head_layer(const unsigned short* __restrict__ in,
                    unsigned short* __restrict__ out,
                    const float* __restrict__ w, const float* __restrict__ bias,
                    int hb, int nb)
{
    const int tid = threadIdx.x, lane = tid & 63, wav = tid >> 6;
    const int tm = wav >> 1, cs = wav & 1;            // 4 row-slots x 2 col-halves
    const int col = cs * 64 + lane;
    half2v wv[64];
#pragma unroll
    for (int i = 0; i < 64; ++i)
        wv[i] = half2v{(_Float16)w[(size_t)(2 * i) * 128 + col],
                       (_Float16)w[(size_t)(2 * i + 1) * 128 + col]};
    const float bb = bias[col];
    for (int r = hb * 4 + tm; r < 64 * CHUNK; r += nb * 4) {
        const unsigned int* ir = (const unsigned int*)(in + (size_t)r * 128);
        unsigned int zw = ir[lane];       // pairs (z[2lane], z[2lane+1])
        float a0 = 0.f, a1 = 0.f;
#pragma unroll
        for (int i = 0; i < 64; i += 2) {
            a0 = dot2(u2h2(rlu(zw, i)),     wv[i],     a0);
            a1 = dot2(u2h2(rlu(zw, i + 1)), wv[i + 1], a1);
        }
        out[(size_t)r * 128 + col] = f2h_bits(gelu_f(a0 + a1 + bb));
    }
}

DEV void head3_layer(const unsigned short* __restrict__ in,
                     const float* __restrict__ w, const float* __restrict__ bias,
                     const unsigned short* __restrict__ xc,
                     const unsigned char* __restrict__ mc,
                     const float* __restrict__ inv2, double* __restrict__ lossacc,
                     int hb, int nb, int hc)
{
    const int tid = threadIdx.x, lane = tid & 63, wav = tid >> 6;
    half2v wv[64];
#pragma unroll
    for (int i = 0; i < 64; ++i)
        wv[i] = half2v{(_Float16)w[(size_t)(2 * i) * 64 + lane],
                       (_Float16)w[(size_t)(2 * i + 1) * 64 + lane]};
    const float bb = bias[lane];
    const float iv = inv2[lane];
    float accf = 0.f; double acc = 0.0; int spill = 0;
    for (int r = hb * 8 + wav; r < 64 * CHUNK; r += nb * 8) {
        const unsigned int* ir = (const unsigned int*)(in + (size_t)r * 128);
        unsigned int zw = ir[lane];
        float a0 = 0.f, a1 = 0.f;
#pragma unroll
        for (int i = 0; i < 64; i += 2) {
            a0 = dot2(u2h2(rlu(zw, i)),     wv[i],     a0);
            a1 = dot2(u2h2(rlu(zw, i + 1)), wv[i + 1], a1);
        }
        float xr = a0 + a1 + bb;
        const int bidx = r >> 9, tl = r & (CHUNK - 1);
        const int t = hc * CHUNK + tl;
        const size_t xb = ((size_t)bidx * 4096 + t) * 64 + lane;
        float dd = xr - bf2f(xc[xb]);
        accf += mc[xb] ? dd * dd * iv : 0.f;
        if (++spill == 64) { acc += (double)accf; accf = 0.f; spill = 0; }
    }
    acc += (double)accf;
    __shared__ double red[512];
    red[tid] = acc;
    __syncthreads();
    for (int s = 256; s > 0; s >>= 1) {
        if (tid < s) red[tid] += red[tid + s];
        __syncthreads();
    }
    if (tid == 0) atomicAdd(lossacc, red[0]);
}

// ---------------- pipelined chunk launch ----------------
// GRU role: R4/R6 one-barrier register-h structure. Three prior attempts
// lost ONLY to regalloc sinking/spilling the 48 weight VGPRs (R4/R6: remat
// into loop; R8: asm-pin -> scratch round-trip). Root cause: the allocator
// TARGETS max occupancy because launch_bounds only sets a MIN waves/EU.
// Fix: amdgpu_waves_per_eu(2,2) caps MAX waves/EU at 2 (= 1 block/CU,
// which the 256-block grid forces anyway) -- occupancy above that is
// impossible, so the heuristic has no reason to economize registers.
__global__ __launch_bounds__(512)
__attribute__((amdgpu_waves_per_eu(2, 2)))
void k_pipe(int c,
    unsigned short* __restrict__ gxring, const unsigned short* __restrict__ h2,
    const float* __restrict__ wih, const float* __restrict__ bih,
    const float* __restrict__ whh, const float* __restrict__ bhh,
    unsigned short* __restrict__ zring, unsigned short* __restrict__ r1ring,
    unsigned short* __restrict__ r2ring, float* __restrict__ hstate,
    const float* __restrict__ h1w, const float* __restrict__ h1b,
    const float* __restrict__ h2w, const float* __restrict__ h2b,
    const float* __restrict__ h3w, const float* __restrict__ h3b,
    const unsigned short* __restrict__ xc, const unsigned char* __restrict__ mc,
    const float* __restrict__ inv2, double* __restrict__ lossacc)
{
    const int tid = threadIdx.x, lane = tid & 63, wav = tid >> 6;

    const int nGru = (c < NCHUNK) ? 64 : 0;
    const int nGx  = (c + 1 < NCHUNK) ? 64 : 0;
    const bool h1On = (c >= 1 && c - 1 < NCHUNK);
    const bool h2On = (c >= 2 && c - 2 < NCHUNK);
    const bool h3On = (c >= 3 && c - 3 < NCHUNK);
    const int rem = 256 - nGru - nGx;
    const int w1 = h1On ? 3 : 0, w2 = h2On ? 3 : 0, w3 = h3On ? 2 : 0;
    const int wsum = w1 + w2 + w3;
    const int n1 = wsum ? rem * w1 / wsum : 0;
    const int n2 = wsum ? rem * w2 / wsum : 0;
    const int n3 = h3On ? rem - n1 - n2 : 0;

    int bid = (int)blockIdx.x;

    if (bid < nGru) {
        // -------- GRU role: 1 batch/block, 1 barrier/step, register h --------
        __shared__ float part[2][4][3][128];   // [parity][ksw][gate][dim]
        const int b = bid;
        const int half = wav & 1, ksw = wav >> 1;
        const int d = half * 64 + lane;
        const int kb = __builtin_amdgcn_readfirstlane(ksw * 16);
        const unsigned short* gxb = gxring + (size_t)(c & 1) * GXCH + (size_t)b * CHUNK * 384;
        unsigned short* zc = zring + (size_t)(c & 1) * RCH + (size_t)b * CHUNK * 128;
        const unsigned int* gx32 = (const unsigned int*)gxb;

        half2v wr[16], wz[16], wn[16];
#pragma unroll
        for (int i = 0; i < 16; ++i) {
            const int k0 = ksw * 32 + 2 * i;
            wr[i] = half2v{(_Float16)whh[(size_t)d * 128 + k0],
                           (_Float16)whh[(size_t)d * 128 + k0 + 1]};
            wz[i] = half2v{(_Float16)whh[(size_t)(128 + d) * 128 + k0],
                           (_Float16)whh[(size_t)(128 + d) * 128 + k0 + 1]};
            wn[i] = half2v{(_Float16)whh[(size_t)(256 + d) * 128 + k0],
                           (_Float16)whh[(size_t)(256 + d) * 128 + k0 + 1]};
        }
        const float bhn0 = bhh[256 + 2 * lane];
        const float bhn1 = bhh[256 + 2 * lane + 1];

        float h0 = 0.f, h1v = 0.f;
        if (c > 0) {
            float2 hv = *(const float2*)(hstate + b * 128 + 2 * lane);
            h0 = hv.x; h1v = hv.y;
        }
        unsigned int hw = (unsigned int)f2h_bits(h0) | ((unsigned int)f2h_bits(h1v) << 16);

        // gx prefetch: u32 pair (2*lane, 2*lane+1) per gate, 4-step blocks.
        // All waves load the SAME addresses -> L1 broadcast.
        unsigned int cur[12], nxt[12];
#pragma unroll
        for (int s = 0; s < 4; ++s)
#pragma unroll
            for (int g = 0; g < 3; ++g) {
                cur[s * 3 + g] = gx32[(size_t)s * 192 + g * 64 + lane];
                nxt[s * 3 + g] = gx32[(size_t)(4 + s) * 192 + g * 64 + lane];
            }

        int p = 0;
        for (int tb = 0; tb < CHUNK / 4; ++tb) {
#pragma unroll
            for (int ti = 0; ti < 4; ++ti) {
                // phase A: k-slice matvec from register h
                float sr = 0.f, sz = 0.f, sn = 0.f;
#pragma unroll
                for (int i = 0; i < 16; ++i) {
                    const half2v hp = u2h2(rlu(hw, kb + i));
                    sr = dot2(hp, wr[i], sr);
                    sz = dot2(hp, wz[i], sz);
                    sn = dot2(hp, wn[i], sn);
                }
                part[p][ksw][0][d] = sr;
                part[p][ksw][1][d] = sz;
                part[p][ksw][2][d] = sn;
                bar_lds();
                // phase B: redundant gate update on ALL waves for pair (2l,2l+1)
                const float2 r0v = ((const float2*)part[p][0][0])[lane];
                const float2 r1v = ((const float2*)part[p][1][0])[lane];
                const float2 r2v = ((const float2*)part[p][2][0])[lane];
                const float2 r3v = ((const float2*)part[p][3][0])[lane];
                const float2 z0v = ((const float2*)part[p][0][1])[lane];
                const float2 z1v = ((const float2*)part[p][1][1])[lane];
                const float2 z2v = ((const float2*)part[p][2][1])[lane];
                const float2 z3v = ((const float2*)part[p][3][1])[lane];
                const float2 n0v = ((const float2*)part[p][0][2])[lane];
                const float2 n1v = ((const float2*)part[p][1][2])[lane];
                const float2 n2v = ((const float2*)part[p][2][2])[lane];
                const float2 n3v = ((const float2*)part[p][3][2])[lane];
                const half2v cr = u2h2(cur[ti * 3 + 0]);
                const half2v cz = u2h2(cur[ti * 3 + 1]);
                const half2v cn = u2h2(cur[ti * 3 + 2]);
                const float gr0 = (r0v.x + r1v.x) + (r2v.x + r3v.x) + (float)cr.x;
                const float gr1 = (r0v.y + r1v.y) + (r2v.y + r3v.y) + (float)cr.y;
                const float gz0 = (z0v.x + z1v.x) + (z2v.x + z3v.x) + (float)cz.x;
                const float gz1 = (z0v.y + z1v.y) + (z2v.y + z3v.y) + (float)cz.y;
                const float gn0 = (n0v.x + n1v.x) + (n2v.x + n3v.x) + bhn0;
                const float gn1 = (n0v.y + n1v.y) + (n2v.y + n3v.y) + bhn1;
                const float rr0 = sigm_f(gr0), rr1 = sigm_f(gr1);
                const float zz0 = sigm_f(gz0), zz1 = sigm_f(gz1);
                const float nn0 = tanh_f((float)cn.x + rr0 * gn0);
                const float nn1 = tanh_f((float)cn.y + rr1 * gn1);
                h0  = nn0 + zz0 * (h0 - nn0);
                h1v = nn1 + zz1 * (h1v - nn1);
                hw = (unsigned int)f2h_bits(h0) | ((unsigned int)f2h_bits(h1v) << 16);
                if (wav == 0)
                    *(unsigned int*)(zc + (size_t)(tb * 4 + ti) * 128 + 2 * lane) = hw;
                p ^= 1;
            }
#pragma unroll
            for (int j = 0; j < 12; ++j) cur[j] = nxt[j];
            const int tnb = (tb + 2 <= CHUNK / 4 - 1) ? (tb + 2) * 4 : (CHUNK - 4);
#pragma unroll
            for (int s = 0; s < 4; ++s)
#pragma unroll
                for (int g = 0; g < 3; ++g)
                    nxt[s * 3 + g] = gx32[(size_t)(tnb + s) * 192 + g * 64 + lane];
        }
        if (wav == 0) {
            float2 hv; hv.x = h0; hv.y = h1v;
            *(float2*)(hstate + b * 128 + 2 * lane) = hv;
        }
        return;
    }
    bid -= nGru;

    if (bid < nGx) {
        // -------- gx role for chunk c+1 (8-way ILP, no serial dep) --------
        if (wav >= 6) return;
        const int b = bid;
        unsigned short* gxd = gxring + (size_t)((c + 1) & 1) * GXCH + (size_t)b * CHUNK * 384;
        const int col = wav * 64 + lane;
        half2v wg[32];
#pragma unroll
        for (int i = 0; i < 32; ++i)
            wg[i] = half2v{(_Float16)wih[(size_t)col * 64 + 2 * i],
                           (_Float16)wih[(size_t)col * 64 + 2 * i + 1]};
        const float gb = bih[col] + (col < 256 ? bhh[col] : 0.f);
        const unsigned int* h232 = (const unsigned int*)h2;
        const size_t hb = ((size_t)b * 4096 + (size_t)(c + 1) * CHUNK) * 32;
        unsigned int hw[8], hn[8];
#pragma unroll
        for (int s = 0; s < 8; ++s)
            hw[s] = h232[hb + (size_t)s * 32 + (lane & 31)];
        for (int t = 0; t < CHUNK; t += 8) {
#pragma unroll
            for (int s = 0; s < 8; ++s) {
                const int tt = t + 8 + s;
                hn[s] = (tt < CHUNK) ? h232[hb + (size_t)tt * 32 + (lane & 31)] : 0u;
            }
            float ss[8] = {0.f, 0.f, 0.f, 0.f, 0.f, 0.f, 0.f, 0.f};
#pragma unroll
            for (int i = 0; i < 32; ++i) {
#pragma unroll
                for (int s = 0; s < 8; ++s)
                    ss[s] = dot2(u2h2(rlu(hw[s], i)), wg[i], ss[s]);
            }
#pragma unroll
            for (int s = 0; s < 8; ++s)
                gxd[(size_t)(t + s) * 384 + col] = f2h_bits(ss[s] + gb);
#pragma unroll
            for (int s = 0; s < 8; ++s) hw[s] = hn[s];
        }
        return;
    }
    bid -= nGx;

    // ---------------- head roles ----------------
    if (bid < n1) {
        const int hc = c - 1;
        head_layer(zring + (size_t)(hc & 1) * RCH, r1ring + (size_t)(hc & 1) * RCH,
                   h1w, h1b, bid, n1);
        return;
    }
    bid -= n1;
    if (bid < n2) {
        const int hc = c - 2;
        head_layer(r1ring + (size_t)(hc & 1) * RCH, r2ring + (size_t)(hc & 1) * RCH,
                   h2w, h2b, bid, n2);
        return;
    }
    bid -= n2;
    if (bid < n3) {
        const int hc = c - 3;
        head3_layer(r2ring + (size_t)(hc & 1) * RCH, h3w, h3b, xc, mc, inv2,
                    lossacc, bid, n3, hc);
    }
}

__global__ void k_loss(const double* __restrict__ acc, const int* __restrict__ flags,
                       void* __restrict__ out)
{
    double cnt = acc[128];
    double denom = (cnt < 1.0) ? 1.0 : cnt;
    float v = (float)(acc[129] / denom);
    if (flags[0] == 1) ((float*)out)[0] = v;
    else ((unsigned short*)out)[0] = f2bf(v);
}

extern "C" void kernel_launch(void* const* d_in, const int* in_sizes, int n_in,
                              void* d_out, int out_size, void* d_ws, size_t ws_size,
                              hipStream_t stream)
{
    (void)in_sizes; (void)n_in; (void)out_size; (void)ws_size;
    const void* x    = d_in[0];
    const void* mask = d_in[1];

    char* ws = (char*)d_ws;
    unsigned short* xc   = (unsigned short*)(ws + OFF_XC);
    unsigned char*  mc   = (unsigned char*)(ws + OFF_MC);
    float*          wc   = (float*)(ws + OFF_WC);
    double*         acc  = (double*)(ws + OFF_ACC);
    int*            cnt  = (int*)(ws + OFF_ACC + 1056);
    int*            flg  = (int*)(ws + OFF_ACC + 1088);
    float*          inv2 = (float*)(ws + OFF_ACC + 1216);
    unsigned short* h2   = (unsigned short*)(ws + OFF_H2);
    unsigned short* gxr  = (unsigned short*)(ws + OFF_GX);
    unsigned short* zr   = (unsigned short*)(ws + OFF_ZR);
    unsigned short* r1r  = (unsigned short*)(ws + OFF_R1);
    unsigned short* r2r  = (unsigned short*)(ws + OFF_R2);
    float*          hst  = (float*)(ws + OFF_HST);

    const float* stem_w = wc + 0;
    const float* stem_b = wc + 4096;
    const float* conv_w = wc + 4160;
    const float* conv_b = wc + 16448;
    const float* w_ih   = wc + 16512;
    const float* w_hh   = wc + 41088;
    const float* b_ih   = wc + 90240;
    const float* b_hh   = wc + 90624;
    const float* h1_w   = wc + 91008;
    const float* h1_b   = wc + 107392;
    const float* h2_w   = wc + 107520;
    const float* h2_b   = wc + 123904;
    const float* h3_w   = wc + 124032;
    const float* h3_b   = wc + 132224;

    hipMemsetAsync(ws + OFF_ACC, 0, 4096, stream);
    k_probe   <<<256, 256, 0, stream>>>((const unsigned short*)x, (const unsigned char*)mask, cnt);
    k_classify<<<1, 1, 0, stream>>>(cnt, flg);
    k_canon_x <<<8192, 256, 0, stream>>>(x, mask, xc, mc, flg);
    k_canon_w <<<14, 256, 0, stream>>>(d_in[2], d_in[3], d_in[4], d_in[5], d_in[6],
                                       d_in[7], d_in[8], d_in[9], d_in[10], d_in[11],
                                       d_in[12], d_in[13], d_in[14], d_in[15], wc, flg);
    k_std     <<<512, 256, 0, stream>>>(xc, mc, acc);
    k_scale   <<<1, 64, 0, stream>>>(acc, inv2);
    k_stemconv<<<1024, 512, 0, stream>>>(xc, mc, stem_w, stem_b, conv_w, conv_b, h2);
    k_gx0     <<<256, 384, 0, stream>>>(h2, w_ih, b_ih, b_hh, gxr);

    for (int c = 0; c < NCHUNK + 3; ++c) {
        k_pipe<<<256, 512, 0, stream>>>(
            c, gxr, h2, w_ih, b_ih, w_hh, b_hh,
            zr, r1r, r2r, hst, h1_w, h1_b, h2_w, h2_b, h3_w, h3_b,
            xc, mc, inv2, acc + 129);
    }
    k_loss<<<1, 1, 0, stream>>>(acc, flg, d_out);
}

// Round 10
// 3335.981 us; speedup vs baseline: 1.5081x; 1.4947x over previous
//
#include <hip/hip_runtime.h>
#include <hip/hip_bf16.h>

#define DEV __device__ __forceinline__

namespace {

constexpr int ROWS = 64 * 4096;        // B*T
constexpr int NE   = ROWS * 64;        // B*T*F
constexpr int CHUNK = 512;
constexpr int NCHUNK = 4096 / CHUNK;   // 8

constexpr size_t GXCH = (size_t)64 * CHUNK * 384;   // elems per gx chunk buf
constexpr size_t RCH  = (size_t)64 * CHUNK * 128;   // elems per z/r1/r2 chunk buf

// workspace layout (bytes), total ~185.1 MB
constexpr size_t OFF_XC  = 0;            // bf16 NE          33,554,432
constexpr size_t OFF_MC  = 33554432;     // u8 NE            16,777,216
constexpr size_t OFF_WC  = 50331648;     // fp32 weights
constexpr size_t OFF_ACC = 50862080;     // 4 KB acc/flags
constexpr size_t OFF_H2  = 50866176;     // f16 NE           33,554,432
constexpr size_t OFF_GX  = 84420608;     // f16 2*GXCH       50,331,648
constexpr size_t OFF_ZR  = 134752256;    // f16 2*RCH        16,777,216
constexpr size_t OFF_R1  = 151529472;    // f16 2*RCH
constexpr size_t OFF_R2  = 168306688;    // f16 2*RCH
constexpr size_t OFF_HST = 185083904;    // fp32 64*128

DEV float rlane(float v, int l) {
    return __int_as_float(__builtin_amdgcn_readlane(__float_as_int(v), l));
}
DEV unsigned int rlu(unsigned int v, int l) {
    return (unsigned int)__builtin_amdgcn_readlane((int)v, l);
}
DEV float bf2f(unsigned short u) { return __uint_as_float(((unsigned int)u) << 16); }
DEV unsigned short f2bf(float f) {
    unsigned int u = __float_as_uint(f);
    unsigned int r = (u + 0x7FFFu + ((u >> 16) & 1u)) >> 16;
    return (unsigned short)r;
}
DEV float gelu_f(float v) { return 0.5f * v * (1.0f + erff(v * 0.70710678118654752f)); }
DEV float sigm_f(float x) { return 1.0f / (1.0f + __expf(-x)); }
DEV float tanh_f(float x) { float t = __expf(2.0f * x); return 1.0f - 2.0f / (t + 1.0f); }

typedef _Float16 half2v __attribute__((ext_vector_type(2)));
typedef __attribute__((ext_vector_type(8))) short bf16x8;
typedef __attribute__((ext_vector_type(4))) float f32x4;

DEV float dot2(half2v a, half2v b, float c) {
#if __has_builtin(__builtin_amdgcn_fdot2)
    return __builtin_amdgcn_fdot2(a, b, c, false);
#else
    return c + (float)a.x * (float)b.x + (float)a.y * (float)b.y;
#endif
}
DEV unsigned short f2h_bits(float f) {
    return __builtin_bit_cast(unsigned short, (_Float16)f);
}
DEV float h2f_bits(unsigned short u) {
    return (float)__builtin_bit_cast(_Float16, u);
}
DEV half2v u2h2(unsigned int p) { return __builtin_bit_cast(half2v, p); }
// LDS-only barrier: skips the vmcnt(0) drain __syncthreads would emit.
DEV void bar_lds() {
    asm volatile("s_waitcnt lgkmcnt(0)\n\ts_barrier" ::: "memory");
}

} // namespace

// ---------------- dtype probe (memory-safe) ----------------
__global__ __launch_bounds__(256) void k_probe(const unsigned short* __restrict__ xh,
    const unsigned char* __restrict__ mb, int* __restrict__ cnt)
{
    const int g = blockIdx.x * 256 + threadIdx.x;
    int hit = 0;
    for (int i = g; i < (1 << 20); i += (1 << 16)) {
        int tb = (xh[i] >> 8) & 0x7F;
        hit += (tb >= 0x3C && tb <= 0x40) ? 1 : 0;
    }
    int a = 0, b = 0, c = 0, d = 0;
    for (int i = g; i < (1 << 24); i += (1 << 16)) {
        unsigned char v = mb[i];
        int r = i & 3;
        a += (v == 1    && r == 0) ? 1 : 0;
        b += (v == 1    && r != 0) ? 1 : 0;
        c += (v == 0x80 && r == 0) ? 1 : 0;
        d += (v == 0x80 && r == 2) ? 1 : 0;
    }
    __shared__ int sm[256];
    int vals[5] = {hit, a, b, c, d};
#pragma unroll
    for (int k = 0; k < 5; ++k) {
        sm[threadIdx.x] = vals[k];
        __syncthreads();
        for (int s = 128; s > 0; s >>= 1) {
            if (threadIdx.x < s) sm[threadIdx.x] += sm[threadIdx.x + s];
            __syncthreads();
        }
        if (threadIdx.x == 0) atomicAdd(cnt + k, sm[0]);
        __syncthreads();
    }
}

__global__ void k_classify(const int* __restrict__ cnt, int* __restrict__ flags)
{
    flags[0] = (cnt[0] > 786432) ? 0 : 1;
    int fm;
    if (cnt[2] > 0) fm = 0;
    else if (cnt[1] > 0) fm = 1;
    else if (cnt[3] > 0) fm = 2;
    else if (cnt[4] > 0) fm = 3;
    else fm = 0;
    flags[1] = fm;
}

// ---------------- canonicalize x (bf16) + mask (u8) ----------------
__global__ __launch_bounds__(256) void k_canon_x(const void* __restrict__ x,
    const void* __restrict__ mask, unsigned short* __restrict__ xc,
    unsigned char* __restrict__ mc, const int* __restrict__ flags)
{
    const int fF = flags[0], fM = flags[1];
    for (int i = blockIdx.x * 256 + threadIdx.x; i < NE; i += gridDim.x * 256) {
        unsigned short h;
        if (fF == 0) h = ((const unsigned short*)x)[i];
        else         h = f2bf(((const float*)x)[i]);
        xc[i] = h;
        unsigned char m;
        if (fM == 0)      m = (((const unsigned char*)mask)[i]  != 0) ? 1 : 0;
        else if (fM == 1) m = (((const int*)mask)[i]            != 0) ? 1 : 0;
        else if (fM == 2) m = (((const unsigned short*)mask)[i] != 0) ? 1 : 0;
        else              m = (((const unsigned int*)mask)[i]   != 0) ? 1 : 0;
        mc[i] = m;
    }
}

// ---------------- canonicalize weights to fp32 ----------------
__global__ __launch_bounds__(256) void k_canon_w(
    const void* p0, const void* p1, const void* p2, const void* p3,
    const void* p4, const void* p5, const void* p6, const void* p7,
    const void* p8, const void* p9, const void* p10, const void* p11,
    const void* p12, const void* p13, float* __restrict__ wc,
    const int* __restrict__ flags)
{
    const int fF = flags[0];
    const void* p; int off, n;
    switch (blockIdx.x) {
        case 0:  p = p0;  off = 0;      n = 4096;  break;  // stem_w
        case 1:  p = p1;  off = 4096;   n = 64;    break;  // stem_b
        case 2:  p = p2;  off = 4160;   n = 12288; break;  // conv_w
        case 3:  p = p3;  off = 16448;  n = 64;    break;  // conv_b
        case 4:  p = p4;  off = 16512;  n = 24576; break;  // w_ih
        case 5:  p = p5;  off = 41088;  n = 49152; break;  // w_hh
        case 6:  p = p6;  off = 90240;  n = 384;   break;  // b_ih
        case 7:  p = p7;  off = 90624;  n = 384;   break;  // b_hh
        case 8:  p = p8;  off = 91008;  n = 16384; break;  // h1_w
        case 9:  p = p9;  off = 107392; n = 128;   break;  // h1_b
        case 10: p = p10; off = 107520; n = 16384; break;  // h2_w
        case 11: p = p11; off = 123904; n = 128;   break;  // h2_b
        case 12: p = p12; off = 124032; n = 8192;  break;  // h3_w
        default: p = p13; off = 132224; n = 64;    break;  // h3_b
    }
    for (int i = threadIdx.x; i < n; i += 256) {
        float v = (fF == 0) ? bf2f(((const unsigned short*)p)[i]) : ((const float*)p)[i];
        wc[off + i] = v;
    }
}

// ---------------- std over features + mask count ----------------
__global__ __launch_bounds__(256) void k_std(const unsigned short* __restrict__ xc,
    const unsigned char* __restrict__ mc, double* __restrict__ acc)
{
    const int tid = threadIdx.x, f = tid & 63, slot = tid >> 6;
    float s = 0.f, sq = 0.f; int cnt = 0;
    for (int row = blockIdx.x * 4 + slot; row < ROWS; row += gridDim.x * 4) {
        const size_t base = (size_t)row * 64 + f;
        float v = bf2f(xc[base]);
        s += v; sq += v * v;
        cnt += mc[base];
    }
    __shared__ float ls[256], lq[256];
    __shared__ int lc[256];
    ls[tid] = s; lq[tid] = sq; lc[tid] = cnt;
    __syncthreads();
    if (tid < 64) {
        float S = ls[tid] + ls[tid + 64] + ls[tid + 128] + ls[tid + 192];
        float Q = lq[tid] + lq[tid + 64] + lq[tid + 128] + lq[tid + 192];
        atomicAdd(acc + tid, (double)S);
        atomicAdd(acc + 64 + tid, (double)Q);
    }
    if (tid == 0) {
        int tot = 0;
        for (int i = 0; i < 256; ++i) tot += lc[i];
        atomicAdd(acc + 128, (double)tot);
    }
}

__global__ void k_scale(const double* __restrict__ acc, float* __restrict__ inv2)
{
    int f = threadIdx.x;
    const double N = (double)ROWS;
    double sum = acc[f], sq = acc[64 + f];
    double var = (sq - sum * sum / N) / (N - 1.0);
    double sd = sqrt(var) + 1e-8;
    inv2[f] = (float)(1.0 / (sd * sd));
}

// ---------------- fused stem + conv via MFMA ----------------
__global__ __launch_bounds__(512) void k_stemconv(const unsigned short* __restrict__ xc,
    const unsigned char* __restrict__ mc, const float* __restrict__ sw,
    const float* __restrict__ sb, const float* __restrict__ cw,
    const float* __restrict__ cb, unsigned short* __restrict__ h2)
{
    __shared__ __align__(16) char smem[2 * 272 * 128];
    char* xs = smem;                  // 272 rows x 64 bf16 (row = t0-1+local)
    char* hs = smem + 272 * 128;      // 272 rows x 64 bf16 (gelu'd stem out)

    const int tid = threadIdx.x, lane = tid & 63, w = tid >> 6;
    const int lr = lane & 15, lk = lane >> 4;       // frag row/col, k-group
    const int ct = w & 3, wh = w >> 2;              // col-tile, row-half
    const int colN = ct * 16 + lr;
    const int b = blockIdx.x >> 4, strip = blockIdx.x & 15, t0 = strip * 256;

    // ---- stage masked x rows [t0-1, t0+256] (locals 0..257; 258..271 zero) ----
    const unsigned short* xb = xc + (size_t)b * 4096 * 64;
    const unsigned char*  mb = mc + (size_t)b * 4096 * 64;
    for (int idx = tid; idx < 272 * 8; idx += 512) {
        const int row = idx >> 3, cc = idx & 7;
        const int t = t0 - 1 + row;
        uint4 xv = {0u, 0u, 0u, 0u};
        if (row < 258 && t >= 0 && t < 4096) {
            const size_t gb = (size_t)t * 64 + cc * 8;
            xv = *(const uint4*)(xb + gb);
            uint2 mv = *(const uint2*)(mb + gb);
            union { uint2 v; unsigned char c[8]; } M; M.v = mv;
            union { uint4 v; unsigned short s[8]; } X; X.v = xv;
#pragma unroll
            for (int j = 0; j < 8; ++j) if (M.c[j]) X.s[j] = 0;
            xv = X.v;
        }
        *(uint4*)(xs + row * 128 + ((cc ^ (row & 7)) << 4)) = xv;
    }

    // ---- B-frags: stem_w (64x64 fp32 -> bf16), lane holds col=colN, k contig ----
    bf16x8 bs[2];
#pragma unroll
    for (int kb = 0; kb < 2; ++kb) {
        bf16x8 f;
#pragma unroll
        for (int j = 0; j < 8; ++j)
            f[j] = (short)f2bf(sw[(size_t)(kb * 32 + lk * 8 + j) * 64 + colN]);
        bs[kb] = f;
    }
    const float sbias = sb[colN];
    // conv B-frags: Bk[i][o] = cw[o*192 + i*3 + k]
    bf16x8 bc[3][2];
#pragma unroll
    for (int k = 0; k < 3; ++k)
#pragma unroll
        for (int kb = 0; kb < 2; ++kb) {
            bf16x8 f;
#pragma unroll
            for (int j = 0; j < 8; ++j)
                f[j] = (short)f2bf(cw[(size_t)colN * 192 + (kb * 32 + lk * 8 + j) * 3 + k]);
            bc[k][kb] = f;
        }
    const float cbias = cb[colN];

    __syncthreads();

    // ---- GEMM1: h = gelu(x @ stem_w + b), 17 row-tiles (272 rows) ----
    for (int rt = wh; rt < 17; rt += 2) {
        const int arow = rt * 16 + lr;
        bf16x8 a0 = *(const bf16x8*)(xs + arow * 128 + (((0 + lk) ^ (arow & 7)) << 4));
        bf16x8 a1 = *(const bf16x8*)(xs + arow * 128 + (((4 + lk) ^ (arow & 7)) << 4));
        f32x4 acc = {0.f, 0.f, 0.f, 0.f};
        acc = __builtin_amdgcn_mfma_f32_16x16x32_bf16(a0, bs[0], acc, 0, 0, 0);
        acc = __builtin_amdgcn_mfma_f32_16x16x32_bf16(a1, bs[1], acc, 0, 0, 0);
#pragma unroll
        for (int j = 0; j < 4; ++j) {
            const int row = rt * 16 + lk * 4 + j;
            if (row < 258) {
                const int t = t0 - 1 + row;
                unsigned short hv = (t >= 0 && t < 4096)
                    ? f2bf(gelu_f(acc[j] + sbias)) : (unsigned short)0;
                *(unsigned short*)(hs + row * 128 +
                    ((((colN >> 3) ^ (row & 7)) << 4)) + (colN & 7) * 2) = hv;
            }
        }
    }
    __syncthreads();

    // ---- GEMM2: out = gelu(sum_k h[t+k-1] @ Wk + cb), 16 out row-tiles ----
    unsigned short* h2b = h2 + ((size_t)b * 4096 + t0) * 64;
    for (int ot = wh; ot < 16; ot += 2) {
        f32x4 acc = {0.f, 0.f, 0.f, 0.f};
#pragma unroll
        for (int k = 0; k < 3; ++k) {
            const int arow = ot * 16 + k + lr;   // h local row = out local + k
            bf16x8 a0 = *(const bf16x8*)(hs + arow * 128 + (((0 + lk) ^ (arow & 7)) << 4));
            bf16x8 a1 = *(const bf16x8*)(hs + arow * 128 + (((4 + lk) ^ (arow & 7)) << 4));
            acc = __builtin_amdgcn_mfma_f32_16x16x32_bf16(a0, bc[k][0], acc, 0, 0, 0);
            acc = __builtin_amdgcn_mfma_f32_16x16x32_bf16(a1, bc[k][1], acc, 0, 0, 0);
        }
#pragma unroll
        for (int j = 0; j < 4; ++j) {
            const int orow = ot * 16 + lk * 4 + j;
            h2b[(size_t)orow * 64 + colN] = f2h_bits(gelu_f(acc[j] + cbias));
        }
    }
}

// ---------------- gx for chunk 0 (standalone, t-split x4, 8-way ILP) --------
__global__ __launch_bounds__(384) void k_gx0(const unsigned short* __restrict__ h2,
    const float* __restrict__ wih, const float* __restrict__ bih,
    const float* __restrict__ bhh, unsigned short* __restrict__ gx0)
{
    const int tid = threadIdx.x, lane = tid & 63, wav = tid >> 6; // 6 waves
    const int col = wav * 64 + lane;
    half2v wg[32];
#pragma unroll
    for (int i = 0; i < 32; ++i)
        wg[i] = half2v{(_Float16)wih[(size_t)col * 64 + 2 * i],
                       (_Float16)wih[(size_t)col * 64 + 2 * i + 1]};
    const float gb = bih[col] + (col < 256 ? bhh[col] : 0.f);
    const unsigned int* h232 = (const unsigned int*)h2;
    const int b = blockIdx.x >> 2, th = (blockIdx.x & 3) * 128;
    const size_t hb = (size_t)b * 4096 * 32;
    unsigned int hw[8], hn[8];
#pragma unroll
    for (int s = 0; s < 8; ++s)
        hw[s] = h232[hb + (size_t)(th + s) * 32 + (lane & 31)];
    for (int t = th; t < th + 128; t += 8) {
#pragma unroll
        for (int s = 0; s < 8; ++s) {
            const int tt = t + 8 + s;
            hn[s] = (tt < th + 128) ? h232[hb + (size_t)tt * 32 + (lane & 31)] : 0u;
        }
        float ss[8] = {0.f, 0.f, 0.f, 0.f, 0.f, 0.f, 0.f, 0.f};
#pragma unroll
        for (int i = 0; i < 32; ++i) {
#pragma unroll
            for (int s = 0; s < 8; ++s)
                ss[s] = dot2(u2h2(rlu(hw[s], i)), wg[i], ss[s]);
        }
#pragma unroll
        for (int s = 0; s < 8; ++s)
            gx0[((size_t)b * CHUNK + t + s) * 384 + col] = f2h_bits(ss[s] + gb);
#pragma unroll
        for (int s = 0; s < 8; ++s) hw[s] = hn[s];
    }
}

// ---------------- head helpers (512 threads = 8 waves) ----------------
DEV void head_layer(const unsigned short* __restrict__ in,
                    unsigned short* __restrict__ out,
                    const float* __restrict__ w, const float* __restrict__ bias,
                    int hb, int nb)
{
    const int tid = threadIdx.x, lane = tid & 63, wav = tid >> 6;
    const int tm = wav >> 1, cs = wav & 1;            // 4 row-slots x 2 col-halves
    const int col = cs * 64 + lane;
    half2v wv[64];
#pragma unroll
    for (int i = 0; i < 64; ++i)
        wv[i] = half2v{(_Float16)w[(size_t)(2 * i) * 128 + col],
                       (_Float16)w[(size_t)(2 * i + 1) * 128 + col]};
    const float bb = bias[col];
    for (int r = hb * 4 + tm; r < 64 * CHUNK; r += nb * 4) {
        const unsigned int* ir = (const unsigned int*)(in + (size_t)r * 128);
        unsigned int zw = ir[lane];       // pairs (z[2lane], z[2lane+1])
        float a0 = 0.f, a1 = 0.f;
#pragma unroll
        for (int i = 0; i < 64; i += 2) {
            a0 = dot2(u2h2(rlu(zw, i)),     wv[i],     a0);
            a1 = dot2(u2h2(rlu(zw, i + 1)), wv[i + 1], a1);
        }
        out[(size_t)r * 128 + col] = f2h_bits(gelu_f(a0 + a1 + bb));
    }
}

DEV void head3_layer(const unsigned short* __restrict__ in,
                     const float* __restrict__ w, const float* __restrict__ bias,
                     const unsigned short* __restrict__ xc,
                     const unsigned char* __restrict__ mc,
                     const float* __restrict__ inv2, double* __restrict__ lossacc,
                     int hb, int nb, int hc)
{
    const int tid = threadIdx.x, lane = tid & 63, wav = tid >> 6;
    half2v wv[64];
#pragma unroll
    for (int i = 0; i < 64; ++i)
        wv[i] = half2v{(_Float16)w[(size_t)(2 * i) * 64 + lane],
                       (_Float16)w[(size_t)(2 * i + 1) * 64 + lane]};
    const float bb = bias[lane];
    const float iv = inv2[lane];
    float accf = 0.f; double acc = 0.0; int spill = 0;
    for (int r = hb * 8 + wav; r < 64 * CHUNK; r += nb * 8) {
        const unsigned int* ir = (const unsigned int*)(in + (size_t)r * 128);
        unsigned int zw = ir[lane];
        float a0 = 0.f, a1 = 0.f;
#pragma unroll
        for (int i = 0; i < 64; i += 2) {
            a0 = dot2(u2h2(rlu(zw, i)),     wv[i],     a0);
            a1 = dot2(u2h2(rlu(zw, i + 1)), wv[i + 1], a1);
        }
        float xr = a0 + a1 + bb;
        const int bidx = r >> 9, tl = r & (CHUNK - 1);
        const int t = hc * CHUNK + tl;
        const size_t xb = ((size_t)bidx * 4096 + t) * 64 + lane;
        float dd = xr - bf2f(xc[xb]);
        accf += mc[xb] ? dd * dd * iv : 0.f;
        if (++spill == 64) { acc += (double)accf; accf = 0.f; spill = 0; }
    }
    acc += (double)accf;
    __shared__ double red[512];
    red[tid] = acc;
    __syncthreads();
    for (int s = 256; s > 0; s >>= 1) {
        if (tid < s) red[tid] += red[tid + s];
        __syncthreads();
    }
    if (tid == 0) atomicAdd(lossacc, red[0]);
}

// ---------------- pipelined chunk launch ----------------
// GRU role: the R1-proven structure VERBATIM (measured 349.5 us steady,
// VGPR=80, no spill/reload): 64 blocks x 8 waves, wave=(ksw,half) k-slice
// matvec with 48 resident weight VGPRs; partials in part[4][3][130];
// phase B (gates) on tid<128; two bar_lds per step; h in LDS hpk.
// Five redesigns (R2-R6, R8-R9) all regressed: spill (R2/R3/R4/R6/R8),
// false overlap (R5), or LDS-throughput blowup from redundant phase-B
// (R9: 96 vs 24 ds_read wave-instrs/step). This is the local optimum.
// gx role: one block per batch, 8-way ILP (no serial dependence).
__global__ __launch_bounds__(512) void k_pipe(int c,
    unsigned short* __restrict__ gxring, const unsigned short* __restrict__ h2,
    const float* __restrict__ wih, const float* __restrict__ bih,
    const float* __restrict__ whh, const float* __restrict__ bhh,
    unsigned short* __restrict__ zring, unsigned short* __restrict__ r1ring,
    unsigned short* __restrict__ r2ring, float* __restrict__ hstate,
    const float* __restrict__ h1w, const float* __restrict__ h1b,
    const float* __restrict__ h2w, const float* __restrict__ h2b,
    const float* __restrict__ h3w, const float* __restrict__ h3b,
    const unsigned short* __restrict__ xc, const unsigned char* __restrict__ mc,
    const float* __restrict__ inv2, double* __restrict__ lossacc)
{
    const int tid = threadIdx.x, lane = tid & 63, wav = tid >> 6;

    const int nGru = (c < NCHUNK) ? 64 : 0;
    const int nGx  = (c + 1 < NCHUNK) ? 64 : 0;
    const bool h1On = (c >= 1 && c - 1 < NCHUNK);
    const bool h2On = (c >= 2 && c - 2 < NCHUNK);
    const bool h3On = (c >= 3 && c - 3 < NCHUNK);
    const int rem = 256 - nGru - nGx;
    const int w1 = h1On ? 3 : 0, w2 = h2On ? 3 : 0, w3 = h3On ? 2 : 0;
    const int wsum = w1 + w2 + w3;
    const int n1 = wsum ? rem * w1 / wsum : 0;
    const int n2 = wsum ? rem * w2 / wsum : 0;
    const int n3 = h3On ? rem - n1 - n2 : 0;

    int bid = (int)blockIdx.x;

    if (bid < nGru) {
        // ---------------- GRU role (R1 k_fused structure) ----------------
        __shared__ float part[4][3][130];
        __shared__ unsigned int hpk[64];   // h as packed f16 pairs
        const int b = bid;
        const int half = wav & 1, ksw = wav >> 1;
        const int d = half * 64 + lane;
        const int kb = __builtin_amdgcn_readfirstlane(ksw * 16);
        const unsigned short* gxb = gxring + (size_t)(c & 1) * GXCH + (size_t)b * CHUNK * 384;
        unsigned short* zc = zring + (size_t)(c & 1) * RCH + (size_t)b * CHUNK * 128;

        half2v wr[16], wz[16], wn[16];
#pragma unroll
        for (int i = 0; i < 16; ++i) {
            const int k0 = ksw * 32 + 2 * i;
            wr[i] = half2v{(_Float16)whh[(size_t)d * 128 + k0],
                           (_Float16)whh[(size_t)d * 128 + k0 + 1]};
            wz[i] = half2v{(_Float16)whh[(size_t)(128 + d) * 128 + k0],
                           (_Float16)whh[(size_t)(128 + d) * 128 + k0 + 1]};
            wn[i] = half2v{(_Float16)whh[(size_t)(256 + d) * 128 + k0],
                           (_Float16)whh[(size_t)(256 + d) * 128 + k0 + 1]};
        }
        const float bhn = bhh[256 + d];

        float hown = 0.0f;
        if (c > 0 && tid < 128) hown = hstate[b * 128 + tid];
        if (tid < 64) {
            float h0 = 0.f, h1v = 0.f;
            if (c > 0) {
                h0  = hstate[b * 128 + 2 * lane];
                h1v = hstate[b * 128 + 2 * lane + 1];
            }
            hpk[lane] = (unsigned int)f2h_bits(h0) | ((unsigned int)f2h_bits(h1v) << 16);
        }
        unsigned short cur[24], nxt[24];
        if (tid < 128) {
#pragma unroll
            for (int ti = 0; ti < 8; ++ti)
#pragma unroll
                for (int g3 = 0; g3 < 3; ++g3) {
                    cur[ti * 3 + g3] = gxb[(size_t)ti * 384 + g3 * 128 + tid];
                    nxt[ti * 3 + g3] = gxb[(size_t)(8 + ti) * 384 + g3 * 128 + tid];
                }
        }
        __syncthreads();

        for (int tb = 0; tb < CHUNK / 8; ++tb) {
#pragma unroll
            for (int ti = 0; ti < 8; ++ti) {
                const unsigned int hw = hpk[lane];
                float sr = 0.f, sz = 0.f, sn = 0.f;
#pragma unroll
                for (int i = 0; i < 16; ++i) {
                    const half2v hp = u2h2(rlu(hw, kb + i));
                    sr = dot2(hp, wr[i], sr);
                    sz = dot2(hp, wz[i], sz);
                    sn = dot2(hp, wn[i], sn);
                }
                part[ksw][0][d] = sr;
                part[ksw][1][d] = sz;
                part[ksw][2][d] = sn;
                bar_lds();
                if (tid < 128) {
                    const float gr  = part[0][0][tid] + part[1][0][tid] + part[2][0][tid]
                                    + part[3][0][tid] + h2f_bits(cur[ti * 3 + 0]);
                    const float gz  = part[0][1][tid] + part[1][1][tid] + part[2][1][tid]
                                    + part[3][1][tid] + h2f_bits(cur[ti * 3 + 1]);
                    const float gnh = part[0][2][tid] + part[1][2][tid] + part[2][2][tid]
                                    + part[3][2][tid] + bhn;
                    const float r  = sigm_f(gr);
                    const float zg = sigm_f(gz);
                    const float n  = tanh_f(h2f_bits(cur[ti * 3 + 2]) + r * gnh);
                    hown = n + zg * (hown - n);
                    ((unsigned short*)hpk)[tid] = f2h_bits(hown);
                    zc[(size_t)(tb * 8 + ti) * 128 + tid] = f2h_bits(hown);
                }
                bar_lds();
            }
            if (tid < 128) {
#pragma unroll
                for (int j = 0; j < 24; ++j) cur[j] = nxt[j];
                const int tnb = (tb + 2 <= CHUNK / 8 - 1) ? (tb + 2) * 8 : (CHUNK - 8);
#pragma unroll
                for (int ti = 0; ti < 8; ++ti)
#pragma unroll
                    for (int g3 = 0; g3 < 3; ++g3)
                        nxt[ti * 3 + g3] = gxb[(size_t)(tnb + ti) * 384 + g3 * 128 + tid];
            }
        }
        if (tid < 128) hstate[b * 128 + tid] = hown;
        return;
    }
    bid -= nGru;

    if (bid < nGx) {
        // -------- gx role for chunk c+1 (8-way ILP, no serial dep) --------
        if (wav >= 6) return;
        const int b = bid;
        unsigned short* gxd = gxring + (size_t)((c + 1) & 1) * GXCH + (size_t)b * CHUNK * 384;
        const int col = wav * 64 + lane;
        half2v wg[32];
#pragma unroll
        for (int i = 0; i < 32; ++i)
            wg[i] = half2v{(_Float16)wih[(size_t)col * 64 + 2 * i],
                           (_Float16)wih[(size_t)col * 64 + 2 * i + 1]};
        const float gb = bih[col] + (col < 256 ? bhh[col] : 0.f);
        const unsigned int* h232 = (const unsigned int*)h2;
        const size_t hb = ((size_t)b * 4096 + (size_t)(c + 1) * CHUNK) * 32;
        unsigned int hw[8], hn[8];
#pragma unroll
        for (int s = 0; s < 8; ++s)
            hw[s] = h232[hb + (size_t)s * 32 + (lane & 31)];
        for (int t = 0; t < CHUNK; t += 8) {
#pragma unroll
            for (int s = 0; s < 8; ++s) {
                const int tt = t + 8 + s;
                hn[s] = (tt < CHUNK) ? h232[hb + (size_t)tt * 32 + (lane & 31)] : 0u;
            }
            float ss[8] = {0.f, 0.f, 0.f, 0.f, 0.f, 0.f, 0.f, 0.f};
#pragma unroll
            for (int i = 0; i < 32; ++i) {
#pragma unroll
                for (int s = 0; s < 8; ++s)
                    ss[s] = dot2(u2h2(rlu(hw[s], i)), wg[i], ss[s]);
            }
#pragma unroll
            for (int s = 0; s < 8; ++s)
                gxd[(size_t)(t + s) * 384 + col] = f2h_bits(ss[s] + gb);
#pragma unroll
            for (int s = 0; s < 8; ++s) hw[s] = hn[s];
        }
        return;
    }
    bid -= nGx;

    // ---------------- head roles ----------------
    if (bid < n1) {
        const int hc = c - 1;
        head_layer(zring + (size_t)(hc & 1) * RCH, r1ring + (size_t)(hc & 1) * RCH,
                   h1w, h1b, bid, n1);
        return;
    }
    bid -= n1;
    if (bid < n2) {
        const int hc = c - 2;
        head_layer(r1ring + (size_t)(hc & 1) * RCH, r2ring + (size_t)(hc & 1) * RCH,
                   h2w, h2b, bid, n2);
        return;
    }
    bid -= n2;
    if (bid < n3) {
        const int hc = c - 3;
        head3_layer(r2ring + (size_t)(hc & 1) * RCH, h3w, h3b, xc, mc, inv2,
                    lossacc, bid, n3, hc);
    }
}

__global__ void k_loss(const double* __restrict__ acc, const int* __restrict__ flags,
                       void* __restrict__ out)
{
    double cnt = acc[128];
    double denom = (cnt < 1.0) ? 1.0 : cnt;
    float v = (float)(acc[129] / denom);
    if (flags[0] == 1) ((float*)out)[0] = v;
    else ((unsigned short*)out)[0] = f2bf(v);
}

extern "C" void kernel_launch(void* const* d_in, const int* in_sizes, int n_in,
                              void* d_out, int out_size, void* d_ws, size_t ws_size,
                              hipStream_t stream)
{
    (void)in_sizes; (void)n_in; (void)out_size; (void)ws_size;
    const void* x    = d_in[0];
    const void* mask = d_in[1];

    char* ws = (char*)d_ws;
    unsigned short* xc   = (unsigned short*)(ws + OFF_XC);
    unsigned char*  mc   = (unsigned char*)(ws + OFF_MC);
    float*          wc   = (float*)(ws + OFF_WC);
    double*         acc  = (double*)(ws + OFF_ACC);
    int*            cnt  = (int*)(ws + OFF_ACC + 1056);
    int*            flg  = (int*)(ws + OFF_ACC + 1088);
    float*          inv2 = (float*)(ws + OFF_ACC + 1216);
    unsigned short* h2   = (unsigned short*)(ws + OFF_H2);
    unsigned short* gxr  = (unsigned short*)(ws + OFF_GX);
    unsigned short* zr   = (unsigned short*)(ws + OFF_ZR);
    unsigned short* r1r  = (unsigned short*)(ws + OFF_R1);
    unsigned short* r2r  = (unsigned short*)(ws + OFF_R2);
    float*          hst  = (float*)(ws + OFF_HST);

    const float* stem_w = wc + 0;
    const float* stem_b = wc + 4096;
    const float* conv_w = wc + 4160;
    const float* conv_b = wc + 16448;
    const float* w_ih   = wc + 16512;
    const float* w_hh   = wc + 41088;
    const float* b_ih   = wc + 90240;
    const float* b_hh   = wc + 90624;
    const float* h1_w   = wc + 91008;
    const float* h1_b   = wc + 107392;
    const float* h2_w   = wc + 107520;
    const float* h2_b   = wc + 123904;
    const float* h3_w   = wc + 124032;
    const float* h3_b   = wc + 132224;

    hipMemsetAsync(ws + OFF_ACC, 0, 4096, stream);
    k_probe   <<<256, 256, 0, stream>>>((const unsigned short*)x, (const unsigned char*)mask, cnt);
    k_classify<<<1, 1, 0, stream>>>(cnt, flg);
    k_canon_x <<<8192, 256, 0, stream>>>(x, mask, xc, mc, flg);
    k_canon_w <<<14, 256, 0, stream>>>(d_in[2], d_in[3], d_in[4], d_in[5], d_in[6],
                                       d_in[7], d_in[8], d_in[9], d_in[10], d_in[11],
                                       d_in[12], d_in[13], d_in[14], d_in[15], wc, flg);
    k_std     <<<512, 256, 0, stream>>>(xc, mc, acc);
    k_scale   <<<1, 64, 0, stream>>>(acc, inv2);
    k_stemconv<<<1024, 512, 0, stream>>>(xc, mc, stem_w, stem_b, conv_w, conv_b, h2);
    k_gx0     <<<256, 384, 0, stream>>>(h2, w_ih, b_ih, b_hh, gxr);

    for (int c = 0; c < NCHUNK + 3; ++c) {
        k_pipe<<<256, 512, 0, stream>>>(
            c, gxr, h2, w_ih, b_ih, w_hh, b_hh,
            zr, r1r, r2r, hst, h1_w, h1_b, h2_w, h2_b, h3_w, h3_b,
            xc, mc, inv2, acc + 129);
    }
    k_loss<<<1, 1, 0, stream>>>(acc, flg, d_out);
}

// Round 12
// 3327.558 us; speedup vs baseline: 1.5119x; 1.0025x over previous
//
#include <hip/hip_runtime.h>
#include <hip/hip_bf16.h>

#define DEV __device__ __forceinline__

namespace {

constexpr int ROWS = 64 * 4096;        // B*T
constexpr int NE   = ROWS * 64;        // B*T*F
constexpr int CHUNK = 512;
constexpr int NCHUNK = 4096 / CHUNK;   // 8

constexpr size_t GXCH = (size_t)64 * CHUNK * 384;   // elems per gx chunk buf
constexpr size_t RCH  = (size_t)64 * CHUNK * 128;   // elems per z/r1/r2 chunk buf

// workspace layout (bytes), total ~185.1 MB
constexpr size_t OFF_XC  = 0;            // bf16 NE          33,554,432
constexpr size_t OFF_MC  = 33554432;     // u8 NE            16,777,216
constexpr size_t OFF_WC  = 50331648;     // fp32 weights
constexpr size_t OFF_ACC = 50862080;     // 4 KB acc/flags
constexpr size_t OFF_H2  = 50866176;     // f16 NE           33,554,432
constexpr size_t OFF_GX  = 84420608;     // f16 2*GXCH       50,331,648
constexpr size_t OFF_ZR  = 134752256;    // f16 2*RCH        16,777,216
constexpr size_t OFF_R1  = 151529472;    // f16 2*RCH
constexpr size_t OFF_R2  = 168306688;    // f16 2*RCH
constexpr size_t OFF_HST = 185083904;    // fp32 64*128

DEV float rlane(float v, int l) {
    return __int_as_float(__builtin_amdgcn_readlane(__float_as_int(v), l));
}
DEV unsigned int rlu(unsigned int v, int l) {
    return (unsigned int)__builtin_amdgcn_readlane((int)v, l);
}
DEV float bf2f(unsigned short u) { return __uint_as_float(((unsigned int)u) << 16); }
DEV unsigned short f2bf(float f) {
    unsigned int u = __float_as_uint(f);
    unsigned int r = (u + 0x7FFFu + ((u >> 16) & 1u)) >> 16;
    return (unsigned short)r;
}
DEV float gelu_f(float v) { return 0.5f * v * (1.0f + erff(v * 0.70710678118654752f)); }
DEV float sigm_f(float x) { return 1.0f / (1.0f + __expf(-x)); }
DEV float tanh_f(float x) { float t = __expf(2.0f * x); return 1.0f - 2.0f / (t + 1.0f); }

typedef _Float16 half2v __attribute__((ext_vector_type(2)));
typedef __attribute__((ext_vector_type(8))) short bf16x8;
typedef __attribute__((ext_vector_type(4))) float f32x4;

DEV float dot2(half2v a, half2v b, float c) {
#if __has_builtin(__builtin_amdgcn_fdot2)
    return __builtin_amdgcn_fdot2(a, b, c, false);
#else
    return c + (float)a.x * (float)b.x + (float)a.y * (float)b.y;
#endif
}
DEV unsigned short f2h_bits(float f) {
    return __builtin_bit_cast(unsigned short, (_Float16)f);
}
DEV float h2f_bits(unsigned short u) {
    return (float)__builtin_bit_cast(_Float16, u);
}
DEV half2v u2h2(unsigned int p) { return __builtin_bit_cast(half2v, p); }
// LDS-only barrier: skips the vmcnt(0) drain __syncthreads would emit.
DEV void bar_lds() {
    asm volatile("s_waitcnt lgkmcnt(0)\n\ts_barrier" ::: "memory");
}

} // namespace

// ---------------- dtype probe (memory-safe) ----------------
__global__ __launch_bounds__(256) void k_probe(const unsigned short* __restrict__ xh,
    const unsigned char* __restrict__ mb, int* __restrict__ cnt)
{
    const int g = blockIdx.x * 256 + threadIdx.x;
    int hit = 0;
    for (int i = g; i < (1 << 20); i += (1 << 16)) {
        int tb = (xh[i] >> 8) & 0x7F;
        hit += (tb >= 0x3C && tb <= 0x40) ? 1 : 0;
    }
    int a = 0, b = 0, c = 0, d = 0;
    for (int i = g; i < (1 << 24); i += (1 << 16)) {
        unsigned char v = mb[i];
        int r = i & 3;
        a += (v == 1    && r == 0) ? 1 : 0;
        b += (v == 1    && r != 0) ? 1 : 0;
        c += (v == 0x80 && r == 0) ? 1 : 0;
        d += (v == 0x80 && r == 2) ? 1 : 0;
    }
    __shared__ int sm[256];
    int vals[5] = {hit, a, b, c, d};
#pragma unroll
    for (int k = 0; k < 5; ++k) {
        sm[threadIdx.x] = vals[k];
        __syncthreads();
        for (int s = 128; s > 0; s >>= 1) {
            if (threadIdx.x < s) sm[threadIdx.x] += sm[threadIdx.x + s];
            __syncthreads();
        }
        if (threadIdx.x == 0) atomicAdd(cnt + k, sm[0]);
        __syncthreads();
    }
}

__global__ void k_classify(const int* __restrict__ cnt, int* __restrict__ flags)
{
    flags[0] = (cnt[0] > 786432) ? 0 : 1;
    int fm;
    if (cnt[2] > 0) fm = 0;
    else if (cnt[1] > 0) fm = 1;
    else if (cnt[3] > 0) fm = 2;
    else if (cnt[4] > 0) fm = 3;
    else fm = 0;
    flags[1] = fm;
}

// ---------------- canonicalize x (bf16) + mask (u8) ----------------
__global__ __launch_bounds__(256) void k_canon_x(const void* __restrict__ x,
    const void* __restrict__ mask, unsigned short* __restrict__ xc,
    unsigned char* __restrict__ mc, const int* __restrict__ flags)
{
    const int fF = flags[0], fM = flags[1];
    for (int i = blockIdx.x * 256 + threadIdx.x; i < NE; i += gridDim.x * 256) {
        unsigned short h;
        if (fF == 0) h = ((const unsigned short*)x)[i];
        else         h = f2bf(((const float*)x)[i]);
        xc[i] = h;
        unsigned char m;
        if (fM == 0)      m = (((const unsigned char*)mask)[i]  != 0) ? 1 : 0;
        else if (fM == 1) m = (((const int*)mask)[i]            != 0) ? 1 : 0;
        else if (fM == 2) m = (((const unsigned short*)mask)[i] != 0) ? 1 : 0;
        else              m = (((const unsigned int*)mask)[i]   != 0) ? 1 : 0;
        mc[i] = m;
    }
}

// ---------------- canonicalize weights to fp32 ----------------
__global__ __launch_bounds__(256) void k_canon_w(
    const void* p0, const void* p1, const void* p2, const void* p3,
    const void* p4, const void* p5, const void* p6, const void* p7,
    const void* p8, const void* p9, const void* p10, const void* p11,
    const void* p12, const void* p13, float* __restrict__ wc,
    const int* __restrict__ flags)
{
    const int fF = flags[0];
    const void* p; int off, n;
    switch (blockIdx.x) {
        case 0:  p = p0;  off = 0;      n = 4096;  break;  // stem_w
        case 1:  p = p1;  off = 4096;   n = 64;    break;  // stem_b
        case 2:  p = p2;  off = 4160;   n = 12288; break;  // conv_w
        case 3:  p = p3;  off = 16448;  n = 64;    break;  // conv_b
        case 4:  p = p4;  off = 16512;  n = 24576; break;  // w_ih
        case 5:  p = p5;  off = 41088;  n = 49152; break;  // w_hh
        case 6:  p = p6;  off = 90240;  n = 384;   break;  // b_ih
        case 7:  p = p7;  off = 90624;  n = 384;   break;  // b_hh
        case 8:  p = p8;  off = 91008;  n = 16384; break;  // h1_w
        case 9:  p = p9;  off = 107392; n = 128;   break;  // h1_b
        case 10: p = p10; off = 107520; n = 16384; break;  // h2_w
        case 11: p = p11; off = 123904; n = 128;   break;  // h2_b
        case 12: p = p12; off = 124032; n = 8192;  break;  // h3_w
        default: p = p13; off = 132224; n = 64;    break;  // h3_b
    }
    for (int i = threadIdx.x; i < n; i += 256) {
        float v = (fF == 0) ? bf2f(((const unsigned short*)p)[i]) : ((const float*)p)[i];
        wc[off + i] = v;
    }
}

// ---------------- std over features + mask count ----------------
__global__ __launch_bounds__(256) void k_std(const unsigned short* __restrict__ xc,
    const unsigned char* __restrict__ mc, double* __restrict__ acc)
{
    const int tid = threadIdx.x, f = tid & 63, slot = tid >> 6;
    float s = 0.f, sq = 0.f; int cnt = 0;
    for (int row = blockIdx.x * 4 + slot; row < ROWS; row += gridDim.x * 4) {
        const size_t base = (size_t)row * 64 + f;
        float v = bf2f(xc[base]);
        s += v; sq += v * v;
        cnt += mc[base];
    }
    __shared__ float ls[256], lq[256];
    __shared__ int lc[256];
    ls[tid] = s; lq[tid] = sq; lc[tid] = cnt;
    __syncthreads();
    if (tid < 64) {
        float S = ls[tid] + ls[tid + 64] + ls[tid + 128] + ls[tid + 192];
        float Q = lq[tid] + lq[tid + 64] + lq[tid + 128] + lq[tid + 192];
        atomicAdd(acc + tid, (double)S);
        atomicAdd(acc + 64 + tid, (double)Q);
    }
    if (tid == 0) {
        int tot = 0;
        for (int i = 0; i < 256; ++i) tot += lc[i];
        atomicAdd(acc + 128, (double)tot);
    }
}

__global__ void k_scale(const double* __restrict__ acc, float* __restrict__ inv2)
{
    int f = threadIdx.x;
    const double N = (double)ROWS;
    double sum = acc[f], sq = acc[64 + f];
    double var = (sq - sum * sum / N) / (N - 1.0);
    double sd = sqrt(var) + 1e-8;
    inv2[f] = (float)(1.0 / (sd * sd));
}

// ---------------- fused stem + conv via MFMA ----------------
__global__ __launch_bounds__(512) void k_stemconv(const unsigned short* __restrict__ xc,
    const unsigned char* __restrict__ mc, const float* __restrict__ sw,
    const float* __restrict__ sb, const float* __restrict__ cw,
    const float* __restrict__ cb, unsigned short* __restrict__ h2)
{
    __shared__ __align__(16) char smem[2 * 272 * 128];
    char* xs = smem;                  // 272 rows x 64 bf16 (row = t0-1+local)
    char* hs = smem + 272 * 128;      // 272 rows x 64 bf16 (gelu'd stem out)

    const int tid = threadIdx.x, lane = tid & 63, w = tid >> 6;
    const int lr = lane & 15, lk = lane >> 4;       // frag row/col, k-group
    const int ct = w & 3, wh = w >> 2;              // col-tile, row-half
    const int colN = ct * 16 + lr;
    const int b = blockIdx.x >> 4, strip = blockIdx.x & 15, t0 = strip * 256;

    // ---- stage masked x rows [t0-1, t0+256] (locals 0..257; 258..271 zero) ----
    const unsigned short* xb = xc + (size_t)b * 4096 * 64;
    const unsigned char*  mb = mc + (size_t)b * 4096 * 64;
    for (int idx = tid; idx < 272 * 8; idx += 512) {
        const int row = idx >> 3, cc = idx & 7;
        const int t = t0 - 1 + row;
        uint4 xv = {0u, 0u, 0u, 0u};
        if (row < 258 && t >= 0 && t < 4096) {
            const size_t gb = (size_t)t * 64 + cc * 8;
            xv = *(const uint4*)(xb + gb);
            uint2 mv = *(const uint2*)(mb + gb);
            union { uint2 v; unsigned char c[8]; } M; M.v = mv;
            union { uint4 v; unsigned short s[8]; } X; X.v = xv;
#pragma unroll
            for (int j = 0; j < 8; ++j) if (M.c[j]) X.s[j] = 0;
            xv = X.v;
        }
        *(uint4*)(xs + row * 128 + ((cc ^ (row & 7)) << 4)) = xv;
    }

    // ---- B-frags: stem_w (64x64 fp32 -> bf16), lane holds col=colN, k contig ----
    bf16x8 bs[2];
#pragma unroll
    for (int kb = 0; kb < 2; ++kb) {
        bf16x8 f;
#pragma unroll
        for (int j = 0; j < 8; ++j)
            f[j] = (short)f2bf(sw[(size_t)(kb * 32 + lk * 8 + j) * 64 + colN]);
        bs[kb] = f;
    }
    const float sbias = sb[colN];
    // conv B-frags: Bk[i][o] = cw[o*192 + i*3 + k]
    bf16x8 bc[3][2];
#pragma unroll
    for (int k = 0; k < 3; ++k)
#pragma unroll
        for (int kb = 0; kb < 2; ++kb) {
            bf16x8 f;
#pragma unroll
            for (int j = 0; j < 8; ++j)
                f[j] = (short)f2bf(cw[(size_t)colN * 192 + (kb * 32 + lk * 8 + j) * 3 + k]);
            bc[k][kb] = f;
        }
    const float cbias = cb[colN];

    __syncthreads();

    // ---- GEMM1: h = gelu(x @ stem_w + b), 17 row-tiles (272 rows) ----
    for (int rt = wh; rt < 17; rt += 2) {
        const int arow = rt * 16 + lr;
        bf16x8 a0 = *(const bf16x8*)(xs + arow * 128 + (((0 + lk) ^ (arow & 7)) << 4));
        bf16x8 a1 = *(const bf16x8*)(xs + arow * 128 + (((4 + lk) ^ (arow & 7)) << 4));
        f32x4 acc = {0.f, 0.f, 0.f, 0.f};
        acc = __builtin_amdgcn_mfma_f32_16x16x32_bf16(a0, bs[0], acc, 0, 0, 0);
        acc = __builtin_amdgcn_mfma_f32_16x16x32_bf16(a1, bs[1], acc, 0, 0, 0);
#pragma unroll
        for (int j = 0; j < 4; ++j) {
            const int row = rt * 16 + lk * 4 + j;
            if (row < 258) {
                const int t = t0 - 1 + row;
                unsigned short hv = (t >= 0 && t < 4096)
                    ? f2bf(gelu_f(acc[j] + sbias)) : (unsigned short)0;
                *(unsigned short*)(hs + row * 128 +
                    ((((colN >> 3) ^ (row & 7)) << 4)) + (colN & 7) * 2) = hv;
            }
        }
    }
    __syncthreads();

    // ---- GEMM2: out = gelu(sum_k h[t+k-1] @ Wk + cb), 16 out row-tiles ----
    unsigned short* h2b = h2 + ((size_t)b * 4096 + t0) * 64;
    for (int ot = wh; ot < 16; ot += 2) {
        f32x4 acc = {0.f, 0.f, 0.f, 0.f};
#pragma unroll
        for (int k = 0; k < 3; ++k) {
            const int arow = ot * 16 + k + lr;   // h local row = out local + k
            bf16x8 a0 = *(const bf16x8*)(hs + arow * 128 + (((0 + lk) ^ (arow & 7)) << 4));
            bf16x8 a1 = *(const bf16x8*)(hs + arow * 128 + (((4 + lk) ^ (arow & 7)) << 4));
            acc = __builtin_amdgcn_mfma_f32_16x16x32_bf16(a0, bc[k][0], acc, 0, 0, 0);
            acc = __builtin_amdgcn_mfma_f32_16x16x32_bf16(a1, bc[k][1], acc, 0, 0, 0);
        }
#pragma unroll
        for (int j = 0; j < 4; ++j) {
            const int orow = ot * 16 + lk * 4 + j;
            h2b[(size_t)orow * 64 + colN] = f2h_bits(gelu_f(acc[j] + cbias));
        }
    }
}

// ---------------- gx for chunk 0 (standalone, t-split x4, 8-way ILP) --------
__global__ __launch_bounds__(384) void k_gx0(const unsigned short* __restrict__ h2,
    const float* __restrict__ wih, const float* __restrict__ bih,
    const float* __restrict__ bhh, unsigned short* __restrict__ gx0)
{
    const int tid = threadIdx.x, lane = tid & 63, wav = tid >> 6; // 6 waves
    const int col = wav * 64 + lane;
    half2v wg[32];
#pragma unroll
    for (int i = 0; i < 32; ++i)
        wg[i] = half2v{(_Float16)wih[(size_t)col * 64 + 2 * i],
                       (_Float16)wih[(size_t)col * 64 + 2 * i + 1]};
    const float gb = bih[col] + (col < 256 ? bhh[col] : 0.f);
    const unsigned int* h232 = (const unsigned int*)h2;
    const int b = blockIdx.x >> 2, th = (blockIdx.x & 3) * 128;
    const size_t hb = (size_t)b * 4096 * 32;
    unsigned int hw[8], hn[8];
#pragma unroll
    for (int s = 0; s < 8; ++s)
        hw[s] = h232[hb + (size_t)(th + s) * 32 + (lane & 31)];
    for (int t = th; t < th + 128; t += 8) {
#pragma unroll
        for (int s = 0; s < 8; ++s) {
            const int tt = t + 8 + s;
            hn[s] = (tt < th + 128) ? h232[hb + (size_t)tt * 32 + (lane & 31)] : 0u;
        }
        float ss[8] = {0.f, 0.f, 0.f, 0.f, 0.f, 0.f, 0.f, 0.f};
#pragma unroll
        for (int i = 0; i < 32; ++i) {
#pragma unroll
            for (int s = 0; s < 8; ++s)
                ss[s] = dot2(u2h2(rlu(hw[s], i)), wg[i], ss[s]);
        }
#pragma unroll
        for (int s = 0; s < 8; ++s)
            gx0[((size_t)b * CHUNK + t + s) * 384 + col] = f2h_bits(ss[s] + gb);
#pragma unroll
        for (int s = 0; s < 8; ++s) hw[s] = hn[s];
    }
}

// ---------------- head helpers (512 threads = 8 waves) ----------------
DEV void head_layer(const unsigned short* __restrict__ in,
                    unsigned short* __restrict__ out,
                    const float* __restrict__ w, const float* __restrict__ bias,
                    int hb, int nb)
{
    const int tid = threadIdx.x, lane = tid & 63, wav = tid >> 6;
    const int tm = wav >> 1, cs = wav & 1;            // 4 row-slots x 2 col-halves
    const int col = cs * 64 + lane;
    half2v wv[64];
#pragma unroll
    for (int i = 0; i < 64; ++i)
        wv[i] = half2v{(_Float16)w[(size_t)(2 * i) * 128 + col],
                       (_Float16)w[(size_t)(2 * i + 1) * 128 + col]};
    const float bb = bias[col];
    for (int r = hb * 4 + tm; r < 64 * CHUNK; r += nb * 4) {
        const unsigned int* ir = (const unsigned int*)(in + (size_t)r * 128);
        unsigned int zw = ir[lane];       // pairs (z[2lane], z[2lane+1])
        float a0 = 0.f, a1 = 0.f;
#pragma unroll
        for (int i = 0; i < 64; i += 2) {
            a0 = dot2(u2h2(rlu(zw, i)),     wv[i],     a0);
            a1 = dot2(u2h2(rlu(zw, i + 1)), wv[i + 1], a1);
        }
        out[(size_t)r * 128 + col] = f2h_bits(gelu_f(a0 + a1 + bb));
    }
}

DEV void head3_layer(const unsigned short* __restrict__ in,
                     const float* __restrict__ w, const float* __restrict__ bias,
                     const unsigned short* __restrict__ xc,
                     const unsigned char* __restrict__ mc,
                     const float* __restrict__ inv2, double* __restrict__ lossacc,
                     int hb, int nb, int hc)
{
    const int tid = threadIdx.x, lane = tid & 63, wav = tid >> 6;
    half2v wv[64];
#pragma unroll
    for (int i = 0; i < 64; ++i)
        wv[i] = half2v{(_Float16)w[(size_t)(2 * i) * 64 + lane],
                       (_Float16)w[(size_t)(2 * i + 1) * 64 + lane]};
    const float bb = bias[lane];
    const float iv = inv2[lane];
    float accf = 0.f; double acc = 0.0; int spill = 0;
    for (int r = hb * 8 + wav; r < 64 * CHUNK; r += nb * 8) {
        const unsigned int* ir = (const unsigned int*)(in + (size_t)r * 128);
        unsigned int zw = ir[lane];
        float a0 = 0.f, a1 = 0.f;
#pragma unroll
        for (int i = 0; i < 64; i += 2) {
            a0 = dot2(u2h2(rlu(zw, i)),     wv[i],     a0);
            a1 = dot2(u2h2(rlu(zw, i + 1)), wv[i + 1], a1);
        }
        float xr = a0 + a1 + bb;
        const int bidx = r >> 9, tl = r & (CHUNK - 1);
        const int t = hc * CHUNK + tl;
        const size_t xb = ((size_t)bidx * 4096 + t) * 64 + lane;
        float dd = xr - bf2f(xc[xb]);
        accf += mc[xb] ? dd * dd * iv : 0.f;
        if (++spill == 64) { acc += (double)accf; accf = 0.f; spill = 0; }
    }
    acc += (double)accf;
    __shared__ double red[512];
    red[tid] = acc;
    __syncthreads();
    for (int s = 256; s > 0; s >>= 1) {
        if (tid < s) red[tid] += red[tid + s];
        __syncthreads();
    }
    if (tid == 0) atomicAdd(lossacc, red[0]);
}

// ---------------- pipelined chunk launch ----------------
// GRU role: the R1-proven structure VERBATIM (measured 347.8 us steady,
// VGPR=80, no spill/reload): 64 blocks x 8 waves, wave=(ksw,half) k-slice
// matvec with 48 resident weight VGPRs; partials in part[4][3][130];
// phase B (gates) on tid<128; two bar_lds per step; h in LDS hpk.
// Six redesigns (R2-R6, R8-R9, R11) regressed or failed: spill
// (R2/R3/R4/R6/R8), false overlap (R5), LDS-throughput blowup (R9),
// harness failure (R11). This is the verified local optimum.
// gx role: one block per batch, 8-way ILP (no serial dependence).
__global__ __launch_bounds__(512) void k_pipe(int c,
    unsigned short* __restrict__ gxring, const unsigned short* __restrict__ h2,
    const float* __restrict__ wih, const float* __restrict__ bih,
    const float* __restrict__ whh, const float* __restrict__ bhh,
    unsigned short* __restrict__ zring, unsigned short* __restrict__ r1ring,
    unsigned short* __restrict__ r2ring, float* __restrict__ hstate,
    const float* __restrict__ h1w, const float* __restrict__ h1b,
    const float* __restrict__ h2w, const float* __restrict__ h2b,
    const float* __restrict__ h3w, const float* __restrict__ h3b,
    const unsigned short* __restrict__ xc, const unsigned char* __restrict__ mc,
    const float* __restrict__ inv2, double* __restrict__ lossacc)
{
    const int tid = threadIdx.x, lane = tid & 63, wav = tid >> 6;

    const int nGru = (c < NCHUNK) ? 64 : 0;
    const int nGx  = (c + 1 < NCHUNK) ? 64 : 0;
    const bool h1On = (c >= 1 && c - 1 < NCHUNK);
    const bool h2On = (c >= 2 && c - 2 < NCHUNK);
    const bool h3On = (c >= 3 && c - 3 < NCHUNK);
    const int rem = 256 - nGru - nGx;
    const int w1 = h1On ? 3 : 0, w2 = h2On ? 3 : 0, w3 = h3On ? 2 : 0;
    const int wsum = w1 + w2 + w3;
    const int n1 = wsum ? rem * w1 / wsum : 0;
    const int n2 = wsum ? rem * w2 / wsum : 0;
    const int n3 = h3On ? rem - n1 - n2 : 0;

    int bid = (int)blockIdx.x;

    if (bid < nGru) {
        // ---------------- GRU role (R1 k_fused structure) ----------------
        __shared__ float part[4][3][130];
        __shared__ unsigned int hpk[64];   // h as packed f16 pairs
        const int b = bid;
        const int half = wav & 1, ksw = wav >> 1;
        const int d = half * 64 + lane;
        const int kb = __builtin_amdgcn_readfirstlane(ksw * 16);
        const unsigned short* gxb = gxring + (size_t)(c & 1) * GXCH + (size_t)b * CHUNK * 384;
        unsigned short* zc = zring + (size_t)(c & 1) * RCH + (size_t)b * CHUNK * 128;

        half2v wr[16], wz[16], wn[16];
#pragma unroll
        for (int i = 0; i < 16; ++i) {
            const int k0 = ksw * 32 + 2 * i;
            wr[i] = half2v{(_Float16)whh[(size_t)d * 128 + k0],
                           (_Float16)whh[(size_t)d * 128 + k0 + 1]};
            wz[i] = half2v{(_Float16)whh[(size_t)(128 + d) * 128 + k0],
                           (_Float16)whh[(size_t)(128 + d) * 128 + k0 + 1]};
            wn[i] = half2v{(_Float16)whh[(size_t)(256 + d) * 128 + k0],
                           (_Float16)whh[(size_t)(256 + d) * 128 + k0 + 1]};
        }
        const float bhn = bhh[256 + d];

        float hown = 0.0f;
        if (c > 0 && tid < 128) hown = hstate[b * 128 + tid];
        if (tid < 64) {
            float h0 = 0.f, h1v = 0.f;
            if (c > 0) {
                h0  = hstate[b * 128 + 2 * lane];
                h1v = hstate[b * 128 + 2 * lane + 1];
            }
            hpk[lane] = (unsigned int)f2h_bits(h0) | ((unsigned int)f2h_bits(h1v) << 16);
        }
        unsigned short cur[24], nxt[24];
        if (tid < 128) {
#pragma unroll
            for (int ti = 0; ti < 8; ++ti)
#pragma unroll
                for (int g3 = 0; g3 < 3; ++g3) {
                    cur[ti * 3 + g3] = gxb[(size_t)ti * 384 + g3 * 128 + tid];
                    nxt[ti * 3 + g3] = gxb[(size_t)(8 + ti) * 384 + g3 * 128 + tid];
                }
        }
        __syncthreads();

        for (int tb = 0; tb < CHUNK / 8; ++tb) {
#pragma unroll
            for (int ti = 0; ti < 8; ++ti) {
                const unsigned int hw = hpk[lane];
                float sr = 0.f, sz = 0.f, sn = 0.f;
#pragma unroll
                for (int i = 0; i < 16; ++i) {
                    const half2v hp = u2h2(rlu(hw, kb + i));
                    sr = dot2(hp, wr[i], sr);
                    sz = dot2(hp, wz[i], sz);
                    sn = dot2(hp, wn[i], sn);
                }
                part[ksw][0][d] = sr;
                part[ksw][1][d] = sz;
                part[ksw][2][d] = sn;
                bar_lds();
                if (tid < 128) {
                    const float gr  = part[0][0][tid] + part[1][0][tid] + part[2][0][tid]
                                    + part[3][0][tid] + h2f_bits(cur[ti * 3 + 0]);
                    const float gz  = part[0][1][tid] + part[1][1][tid] + part[2][1][tid]
                                    + part[3][1][tid] + h2f_bits(cur[ti * 3 + 1]);
                    const float gnh = part[0][2][tid] + part[1][2][tid] + part[2][2][tid]
                                    + part[3][2][tid] + bhn;
                    const float r  = sigm_f(gr);
                    const float zg = sigm_f(gz);
                    const float n  = tanh_f(h2f_bits(cur[ti * 3 + 2]) + r * gnh);
                    hown = n + zg * (hown - n);
                    ((unsigned short*)hpk)[tid] = f2h_bits(hown);
                    zc[(size_t)(tb * 8 + ti) * 128 + tid] = f2h_bits(hown);
                }
                bar_lds();
            }
            if (tid < 128) {
#pragma unroll
                for (int j = 0; j < 24; ++j) cur[j] = nxt[j];
                const int tnb = (tb + 2 <= CHUNK / 8 - 1) ? (tb + 2) * 8 : (CHUNK - 8);
#pragma unroll
                for (int ti = 0; ti < 8; ++ti)
#pragma unroll
                    for (int g3 = 0; g3 < 3; ++g3)
                        nxt[ti * 3 + g3] = gxb[(size_t)(tnb + ti) * 384 + g3 * 128 + tid];
            }
        }
        if (tid < 128) hstate[b * 128 + tid] = hown;
        return;
    }
    bid -= nGru;

    if (bid < nGx) {
        // -------- gx role for chunk c+1 (8-way ILP, no serial dep) --------
        if (wav >= 6) return;
        const int b = bid;
        unsigned short* gxd = gxring + (size_t)((c + 1) & 1) * GXCH + (size_t)b * CHUNK * 384;
        const int col = wav * 64 + lane;
        half2v wg[32];
#pragma unroll
        for (int i = 0; i < 32; ++i)
            wg[i] = half2v{(_Float16)wih[(size_t)col * 64 + 2 * i],
                           (_Float16)wih[(size_t)col * 64 + 2 * i + 1]};
        const float gb = bih[col] + (col < 256 ? bhh[col] : 0.f);
        const unsigned int* h232 = (const unsigned int*)h2;
        const size_t hb = ((size_t)b * 4096 + (size_t)(c + 1) * CHUNK) * 32;
        unsigned int hw[8], hn[8];
#pragma unroll
        for (int s = 0; s < 8; ++s)
            hw[s] = h232[hb + (size_t)s * 32 + (lane & 31)];
        for (int t = 0; t < CHUNK; t += 8) {
#pragma unroll
            for (int s = 0; s < 8; ++s) {
                const int tt = t + 8 + s;
                hn[s] = (tt < CHUNK) ? h232[hb + (size_t)tt * 32 + (lane & 31)] : 0u;
            }
            float ss[8] = {0.f, 0.f, 0.f, 0.f, 0.f, 0.f, 0.f, 0.f};
#pragma unroll
            for (int i = 0; i < 32; ++i) {
#pragma unroll
                for (int s = 0; s < 8; ++s)
                    ss[s] = dot2(u2h2(rlu(hw[s], i)), wg[i], ss[s]);
            }
#pragma unroll
            for (int s = 0; s < 8; ++s)
                gxd[(size_t)(t + s) * 384 + col] = f2h_bits(ss[s] + gb);
#pragma unroll
            for (int s = 0; s < 8; ++s) hw[s] = hn[s];
        }
        return;
    }
    bid -= nGx;

    // ---------------- head roles ----------------
    if (bid < n1) {
        const int hc = c - 1;
        head_layer(zring + (size_t)(hc & 1) * RCH, r1ring + (size_t)(hc & 1) * RCH,
                   h1w, h1b, bid, n1);
        return;
    }
    bid -= n1;
    if (bid < n2) {
        const int hc = c - 2;
        head_layer(r1ring + (size_t)(hc & 1) * RCH, r2ring + (size_t)(hc & 1) * RCH,
                   h2w, h2b, bid, n2);
        return;
    }
    bid -= n2;
    if (bid < n3) {
        const int hc = c - 3;
        head3_layer(r2ring + (size_t)(hc & 1) * RCH, h3w, h3b, xc, mc, inv2,
                    lossacc, bid, n3, hc);
    }
}

__global__ void k_loss(const double* __restrict__ acc, const int* __restrict__ flags,
                       void* __restrict__ out)
{
    double cnt = acc[128];
    double denom = (cnt < 1.0) ? 1.0 : cnt;
    float v = (float)(acc[129] / denom);
    if (flags[0] == 1) ((float*)out)[0] = v;
    else ((unsigned short*)out)[0] = f2bf(v);
}

extern "C" void kernel_launch(void* const* d_in, const int* in_sizes, int n_in,
                              void* d_out, int out_size, void* d_ws, size_t ws_size,
                              hipStream_t stream)
{
    (void)in_sizes; (void)n_in; (void)out_size; (void)ws_size;
    const void* x    = d_in[0];
    const void* mask = d_in[1];

    char* ws = (char*)d_ws;
    unsigned short* xc   = (unsigned short*)(ws + OFF_XC);
    unsigned char*  mc   = (unsigned char*)(ws + OFF_MC);
    float*          wc   = (float*)(ws + OFF_WC);
    double*         acc  = (double*)(ws + OFF_ACC);
    int*            cnt  = (int*)(ws + OFF_ACC + 1056);
    int*            flg  = (int*)(ws + OFF_ACC + 1088);
    float*          inv2 = (float*)(ws + OFF_ACC + 1216);
    unsigned short* h2   = (unsigned short*)(ws + OFF_H2);
    unsigned short* gxr  = (unsigned short*)(ws + OFF_GX);
    unsigned short* zr   = (unsigned short*)(ws + OFF_ZR);
    unsigned short* r1r  = (unsigned short*)(ws + OFF_R1);
    unsigned short* r2r  = (unsigned short*)(ws + OFF_R2);
    float*          hst  = (float*)(ws + OFF_HST);

    const float* stem_w = wc + 0;
    const float* stem_b = wc + 4096;
    const float* conv_w = wc + 4160;
    const float* conv_b = wc + 16448;
    const float* w_ih   = wc + 16512;
    const float* w_hh   = wc + 41088;
    const float* b_ih   = wc + 90240;
    const float* b_hh   = wc + 90624;
    const float* h1_w   = wc + 91008;
    const float* h1_b   = wc + 107392;
    const float* h2_w   = wc + 107520;
    const float* h2_b   = wc + 123904;
    const float* h3_w   = wc + 124032;
    const float* h3_b   = wc + 132224;

    hipMemsetAsync(ws + OFF_ACC, 0, 4096, stream);
    k_probe   <<<256, 256, 0, stream>>>((const unsigned short*)x, (const unsigned char*)mask, cnt);
    k_classify<<<1, 1, 0, stream>>>(cnt, flg);
    k_canon_x <<<8192, 256, 0, stream>>>(x, mask, xc, mc, flg);
    k_canon_w <<<14, 256, 0, stream>>>(d_in[2], d_in[3], d_in[4], d_in[5], d_in[6],
                                       d_in[7], d_in[8], d_in[9], d_in[10], d_in[11],
                                       d_in[12], d_in[13], d_in[14], d_in[15], wc, flg);
    k_std     <<<512, 256, 0, stream>>>(xc, mc, acc);
    k_scale   <<<1, 64, 0, stream>>>(acc, inv2);
    k_stemconv<<<1024, 512, 0, stream>>>(xc, mc, stem_w, stem_b, conv_w, conv_b, h2);
    k_gx0     <<<256, 384, 0, stream>>>(h2, w_ih, b_ih, b_hh, gxr);

    for (int c = 0; c < NCHUNK + 3; ++c) {
        k_pipe<<<256, 512, 0, stream>>>(
            c, gxr, h2, w_ih, b_ih, w_hh, b_hh,
            zr, r1r, r2r, hst, h1_w, h1_b, h2_w, h2_b, h3_w, h3_b,
            xc, mc, inv2, acc + 129);
    }
    k_loss<<<1, 1, 0, stream>>>(acc, flg, d_out);
}